// Round 4
// baseline (694.786 us; speedup 1.0000x reference)
//
#include <hip/hip_runtime.h>
#include <hip/hip_bf16.h>
#include <cstdint>
#include <cstddef>

#define N_NODES 50000
#define N_EDGES 800000

typedef __attribute__((ext_vector_type(8))) short short8;
typedef __attribute__((ext_vector_type(4))) float floatx4;
typedef __attribute__((ext_vector_type(4))) unsigned int uintx4;

__device__ inline float bf2f(unsigned short u) {
    union { unsigned int i; float f; } v; v.i = ((unsigned int)u) << 16; return v.f;
}
__device__ inline unsigned short f2bf(float f) {
    union { float f; unsigned int i; } v; v.f = f;
    unsigned int u = v.i;
    return (unsigned short)((u + 0x7FFFu + ((u >> 16) & 1u)) >> 16);
}
// silu via v_rcp_f32 (1 ulp) instead of IEEE divide
__device__ inline float silu_f(float x) {
    float e = __expf(-x);
    return x * __builtin_amdgcn_rcpf(1.0f + e);
}

// ---------------------------------------------------------------------------
// Pack kernel: fp32->bf16 conversions + weight rearrangement into MFMA
// B-fragment order: Bp[(kb*NOUT + n)*8 + i] = B[(kb*8+i)*NOUT + n]
// ---------------------------------------------------------------------------
__device__ inline void pack_std(const float* __restrict__ src,
                                unsigned short* __restrict__ dst,
                                int NOUT, long j) {
    int i = (int)(j & 7);
    long rest = j >> 3;
    int n = (int)(rest % NOUT);
    int kb = (int)(rest / NOUT);
    dst[j] = f2bf(src[(long)(kb * 8 + i) * NOUT + n]);
}

#define NH0   (N_NODES * 64L)
#define SW_IN 8192L
#define SW_OUT 8192L
#define SW1   16384L
#define SE2   4096L
#define SN1   24576L
#define SN2   16384L
#define SB    128L
#define PERL  (SW1 + SE2 + SN1 + SN2 + SB)
#define PACK_TOTAL (NH0 + SW_IN + SW_OUT + 4 * PERL)

__global__ __launch_bounds__(256) void pack_kernel(
    const float* __restrict__ h0, const float* __restrict__ W_in,
    const float* __restrict__ W_out, const float* __restrict__ eW1,
    const float* __restrict__ eb1, const float* __restrict__ eW2,
    const float* __restrict__ nW1, const float* __restrict__ nW2,
    unsigned short* __restrict__ h0bf, unsigned short* __restrict__ Winp,
    unsigned short* __restrict__ Woutp, unsigned short* __restrict__ W1p,
    unsigned short* __restrict__ eW2p, unsigned short* __restrict__ nW1p,
    unsigned short* __restrict__ nW2p, float* __restrict__ biasP)
{
    long idx = (long)blockIdx.x * 256 + threadIdx.x;
    if (idx >= PACK_TOTAL) return;
    long j = idx;
    if (j < NH0) { h0bf[j] = f2bf(h0[j]); return; }
    j -= NH0;
    if (j < SW_IN) { pack_std(W_in, Winp, 128, j); return; }
    j -= SW_IN;
    if (j < SW_OUT) { pack_std(W_out, Woutp, 64, j); return; }
    j -= SW_OUT;
    int l = (int)(j / PERL);
    long r = j % PERL;
    if (r < SW1) {
        int i = (int)(r & 7);
        int n = (int)((r >> 3) & 127);
        int kb = (int)(r >> 10);
        int k = kb * 8 + i;
        const float* w = eW1 + (long)l * 256 * 64;
        float v = (n < 64) ? w[(long)k * 64 + n] : w[(long)(128 + k) * 64 + (n - 64)];
        W1p[(long)l * SW1 + r] = f2bf(v);
        return;
    }
    r -= SW1;
    if (r < SE2) { pack_std(eW2 + (long)l * 4096, eW2p + (long)l * SE2, 64, r); return; }
    r -= SE2;
    if (r < SN1) { pack_std(nW1 + (long)l * 24576, nW1p + (long)l * SN1, 128, r); return; }
    r -= SN1;
    if (r < SN2) { pack_std(nW2 + (long)l * 16384, nW2p + (long)l * SN2, 128, r); return; }
    r -= SN2;
    biasP[(long)l * 128 + r] = (r < 64) ? eb1[(long)l * 64 + r] : 0.0f;
}

// ---------------------------------------------------------------------------
// CSR build kernels (once per launch)
// ---------------------------------------------------------------------------
__global__ __launch_bounds__(256) void hist_k(const int* __restrict__ erow,
                                              int* __restrict__ counts, int E) {
    int e = blockIdx.x * 256 + threadIdx.x;
    if (e < E) atomicAdd(&counts[erow[e]], 1);
}

__global__ __launch_bounds__(1024) void scan1_k(const int* __restrict__ counts,
                                                int* __restrict__ cursor,
                                                int* __restrict__ bsum, int n) {
    __shared__ int buf[1024];
    int i = blockIdx.x * 1024 + threadIdx.x;
    int v = (i < n) ? counts[i] : 0;
    buf[threadIdx.x] = v;
    __syncthreads();
    #pragma unroll
    for (int off = 1; off < 1024; off <<= 1) {
        int t = (threadIdx.x >= off) ? buf[threadIdx.x - off] : 0;
        __syncthreads();
        buf[threadIdx.x] += t;
        __syncthreads();
    }
    if (i < n) cursor[i] = buf[threadIdx.x] - v;
    if (threadIdx.x == 1023) bsum[blockIdx.x] = buf[1023];
}

__global__ __launch_bounds__(64) void scan2_k(int* __restrict__ bsum, int nb) {
    __shared__ int b[64];
    int tid = threadIdx.x;
    int v = (tid < nb) ? bsum[tid] : 0;
    b[tid] = v;
    __syncthreads();
    #pragma unroll
    for (int off = 1; off < 64; off <<= 1) {
        int t = (tid >= off) ? b[tid - off] : 0;
        __syncthreads();
        b[tid] += t;
        __syncthreads();
    }
    if (tid < nb) bsum[tid] = b[tid] - v;
}

__global__ __launch_bounds__(1024) void scan3_k(int* __restrict__ cursor,
                                                const int* __restrict__ bsum, int n) {
    int i = blockIdx.x * 1024 + threadIdx.x;
    if (i < n) cursor[i] += bsum[blockIdx.x];
}

__global__ __launch_bounds__(256) void scatter_k(const int* __restrict__ erow,
                                                 const int* __restrict__ ecol,
                                                 int* __restrict__ cursor,
                                                 int* __restrict__ rowS,
                                                 int* __restrict__ colS, int E) {
    int e = blockIdx.x * 256 + threadIdx.x;
    if (e < E) {
        int r = erow[e];
        int s = atomicAdd(&cursor[r], 1);
        rowS[s] = r;
        colS[s] = ecol[e];
    }
}

// ---------------------------------------------------------------------------
// Fused edge + per-wave segmented aggregate over CSR-sorted edges.
// ZERO __syncthreads: each wave owns 16 edge rows end-to-end. Segments
// interior to a wave's window -> plain store; window-boundary -> atomicAdd.
// agg must be pre-zeroed (done in tail of previous node/embed kernel).
// ---------------------------------------------------------------------------
__global__ __launch_bounds__(256) void edge_fused_k(
    const int* __restrict__ rowS, const int* __restrict__ colS,
    const unsigned short* __restrict__ P,    // [N,128]: 0..63 top(+b1), 64..127 bot
    const unsigned short* __restrict__ Bp,   // eW2 frag order
    const float* __restrict__ b2, float* __restrict__ agg, int E)
{
    __shared__ unsigned short Ms[64 * 72];
    __shared__ float M2s[64 * 68];
    __shared__ int ridS[64];
    const int tid = threadIdx.x;
    const int wave = tid >> 6;
    const int lane = tid & 63;
    const int e0 = blockIdx.x * 64;

    // stage 1: gather endpoints, silu(Ptop[row]+Pbot[col]) -> Ms (bf16).
    // Thread tid handles edge el = tid>>2 (wave-private rows [16w,16w+16)).
    {
        int el = tid >> 2;
        int part = tid & 3;
        int s = e0 + el;
        if (s < E) {
            int rr = rowS[s], cc = colS[s];
            if (part == 0) ridS[el] = rr;
            const uintx4* pt = (const uintx4*)(P + (size_t)rr * 128 + part * 16);
            const uintx4* pb = (const uintx4*)(P + (size_t)cc * 128 + 64 + part * 16);
            #pragma unroll
            for (int h = 0; h < 2; h++) {
                uintx4 a = pt[h], b = pb[h];
                const unsigned short* au = (const unsigned short*)&a;
                const unsigned short* bu = (const unsigned short*)&b;
                unsigned short o[8];
                #pragma unroll
                for (int i = 0; i < 8; i++) {
                    float x = bf2f(au[i]) + bf2f(bu[i]);
                    o[i] = f2bf(silu_f(x));
                }
                *(uintx4*)(&Ms[el * 72 + part * 16 + h * 8]) = *(const uintx4*)o;
            }
        } else if (part == 0) {
            ridS[el] = -1;
        }
    }
    // no barrier: Ms/ridS rows are wave-private (same-wave LDS RAW ordering)

    // stage 2: m2 = Ms @ eW2 via MFMA (wave computes its own 16 rows)
    const int lrow = lane & 15;
    const int quad = lane >> 4;

    floatx4 acc[4];
    #pragma unroll
    for (int i = 0; i < 4; i++) acc[i] = (floatx4){0, 0, 0, 0};

    const unsigned short* arow = &Ms[(wave * 16 + lrow) * 72];
    #pragma unroll
    for (int kt = 0; kt < 2; kt++) {
        short8 afrag = *(const short8*)(arow + kt * 32 + quad * 8);
        int kb = kt * 4 + quad;
        #pragma unroll
        for (int nt = 0; nt < 4; nt++) {
            short8 bfrag = *(const short8*)(Bp + (size_t)(kb * 64 + nt * 16 + lrow) * 8);
            acc[nt] = __builtin_amdgcn_mfma_f32_16x16x32_bf16(afrag, bfrag, acc[nt], 0, 0, 0);
        }
    }

    // stage 3: silu(m2 + b2) -> M2s (fp32), wave-private rows
    #pragma unroll
    for (int nt = 0; nt < 4; nt++) {
        int n = nt * 16 + lrow;
        float bv = b2[n];
        #pragma unroll
        for (int r = 0; r < 4; r++) {
            int el = wave * 16 + quad * 4 + r;
            M2s[el * 68 + n] = silu_f(acc[nt][r] + bv);
        }
    }

    // stage 4: per-wave segmented reduce. lane = feature (64).
    // Segment starting at el>0 and ending before window end is exclusive
    // to this wave (rows globally sorted & contiguous) -> plain store.
    // Window-boundary segments -> atomicAdd onto zeroed agg.
    {
        int base = wave * 16;
        float s = 0.0f;
        int cur = ridS[base];
        int a0 = 0;
        for (int el = 0; el < 16; el++) {
            int rv = ridS[base + el];
            if (rv != cur) {                      // uniform across wave
                if (cur >= 0) {
                    if (a0 == 0) atomicAdd(&agg[(size_t)cur * 64 + lane], s);
                    else         agg[(size_t)cur * 64 + lane] = s;
                }
                s = 0.0f; cur = rv; a0 = el;
            }
            if (rv >= 0) s += M2s[(base + el) * 68 + lane];
        }
        if (cur >= 0) atomicAdd(&agg[(size_t)cur * 64 + lane], s);
    }
}

// ---------------------------------------------------------------------------
// Fused node-side chain, barrier-minimal: ONE __syncthreads (after staging).
// All LDS rows are wave-private afterwards (wave w owns rows [16w,16w+16)
// at unified stride 200 across all three phases).
//   t     = silu([h | agg] @ nW1 + nb1)      (K=192 -> 128)
//   h_new = h + t @ nW2 + nb2                (resid prefetched into regs)
//   FINAL=0: P = h_new @ W1'[l+1] + biasP ; FINAL=1: out = h_new @ W_out
// Tail: grid-stride zero of next layer's agg buffer (aggZ, may be null).
// ---------------------------------------------------------------------------
template<int FINAL>
__global__ __launch_bounds__(256, 3) void node_fused_k(
    const unsigned short* __restrict__ hbf, const float* __restrict__ agg,
    const unsigned short* __restrict__ W1, const float* __restrict__ b1,
    const unsigned short* __restrict__ W2, const float* __restrict__ b2,
    const unsigned short* __restrict__ B3, const float* __restrict__ bias3,
    float* __restrict__ hF, unsigned short* __restrict__ hB,
    unsigned short* __restrict__ Pout, float* __restrict__ outF,
    float* __restrict__ aggZ, int M)
{
    __shared__ unsigned short S[64 * 200];
    const int tid = threadIdx.x;
    const int m0 = blockIdx.x * 64;
    const int wave = tid >> 6;
    const int lane = tid & 63;
    const int lrow = lane & 15;
    const int quad = lane >> 4;

    // prefetch residual h (fp32) early: latency overlaps staging + barrier
    float res[8][4];
    #pragma unroll
    for (int nt = 0; nt < 8; nt++) {
        #pragma unroll
        for (int r = 0; r < 4; r++) {
            int row = m0 + wave * 16 + quad * 4 + r;
            res[nt][r] = (row < M) ? hF[(size_t)row * 128 + nt * 16 + lrow] : 0.0f;
        }
    }

    // staging: [h(128 bf16) | agg(64 fp32->bf16)] -> S rows, stride 200
    for (int t = tid; t < 64 * 24; t += 256) {
        int rr = t / 24, c = t % 24;
        int row = m0 + rr;
        uintx4 val = {0, 0, 0, 0};
        if (row < M) {
            if (c < 16) {
                val = *(const uintx4*)(hbf + (size_t)row * 128 + c * 8);
            } else {
                const floatx4* s4 = (const floatx4*)(agg + (size_t)row * 64 + (c - 16) * 8);
                floatx4 f0 = s4[0], f1 = s4[1];
                unsigned short tmp[8];
                #pragma unroll
                for (int i = 0; i < 4; i++) { tmp[i] = f2bf(f0[i]); tmp[4 + i] = f2bf(f1[i]); }
                val = *(const uintx4*)tmp;
            }
        }
        *(uintx4*)(&S[rr * 200 + c * 8]) = val;
    }
    __syncthreads();   // the only barrier

    // ---- phase A MFMA: K=192, NOUT=128 ----
    floatx4 acc[8];
    #pragma unroll
    for (int i = 0; i < 8; i++) acc[i] = (floatx4){0, 0, 0, 0};
    {
        const unsigned short* arow = &S[(wave * 16 + lrow) * 200];
        #pragma unroll
        for (int kt = 0; kt < 6; kt++) {
            short8 afrag = *(const short8*)(arow + kt * 32 + quad * 8);
            int kb = kt * 4 + quad;
            #pragma unroll
            for (int nt = 0; nt < 8; nt++) {
                short8 bfrag = *(const short8*)(W1 + (size_t)(kb * 128 + nt * 16 + lrow) * 8);
                acc[nt] = __builtin_amdgcn_mfma_f32_16x16x32_bf16(afrag, bfrag, acc[nt], 0, 0, 0);
            }
        }
    }

    // epilogue A: t -> own S rows (cols 0..127), same stride
    #pragma unroll
    for (int nt = 0; nt < 8; nt++) {
        int n = nt * 16 + lrow;
        float bv = b1[n];
        #pragma unroll
        for (int r = 0; r < 4; r++) {
            int el = wave * 16 + quad * 4 + r;
            S[el * 200 + n] = f2bf(silu_f(acc[nt][r] + bv));
        }
    }

    // ---- phase B MFMA: K=128, NOUT=128 ----
    floatx4 acc2[8];
    #pragma unroll
    for (int i = 0; i < 8; i++) acc2[i] = (floatx4){0, 0, 0, 0};
    {
        const unsigned short* arow = &S[(wave * 16 + lrow) * 200];
        #pragma unroll
        for (int kt = 0; kt < 4; kt++) {
            short8 afrag = *(const short8*)(arow + kt * 32 + quad * 8);
            int kb = kt * 4 + quad;
            #pragma unroll
            for (int nt = 0; nt < 8; nt++) {
                short8 bfrag = *(const short8*)(W2 + (size_t)(kb * 128 + nt * 16 + lrow) * 8);
                acc2[nt] = __builtin_amdgcn_mfma_f32_16x16x32_bf16(afrag, bfrag, acc2[nt], 0, 0, 0);
            }
        }
    }

    // epilogue B: h_new = acc2 + b2 + res -> globals + own S rows
    #pragma unroll
    for (int nt = 0; nt < 8; nt++) {
        int n = nt * 16 + lrow;
        float bv = b2[n];
        #pragma unroll
        for (int r = 0; r < 4; r++) {
            int el = wave * 16 + quad * 4 + r;
            int row = m0 + el;
            float v = acc2[nt][r] + bv + res[nt][r];
            unsigned short vb = f2bf(v);
            S[el * 200 + n] = vb;
            if (row < M) {
                hF[(size_t)row * 128 + n] = v;
                hB[(size_t)row * 128 + n] = vb;
            }
        }
    }

    // ---- phase C MFMA: K=128 -> P (128) or out (64) ----
    constexpr int NT3 = FINAL ? 4 : 8;
    constexpr int NO3 = FINAL ? 64 : 128;
    floatx4 acc3[NT3];
    #pragma unroll
    for (int i = 0; i < NT3; i++) acc3[i] = (floatx4){0, 0, 0, 0};
    {
        const unsigned short* arow = &S[(wave * 16 + lrow) * 200];
        #pragma unroll
        for (int kt = 0; kt < 4; kt++) {
            short8 afrag = *(const short8*)(arow + kt * 32 + quad * 8);
            int kb = kt * 4 + quad;
            #pragma unroll
            for (int nt = 0; nt < NT3; nt++) {
                short8 bfrag = *(const short8*)(B3 + (size_t)(kb * NO3 + nt * 16 + lrow) * 8);
                acc3[nt] = __builtin_amdgcn_mfma_f32_16x16x32_bf16(afrag, bfrag, acc3[nt], 0, 0, 0);
            }
        }
    }
    #pragma unroll
    for (int nt = 0; nt < NT3; nt++) {
        int n = nt * 16 + lrow;
        float bv = bias3[n];
        #pragma unroll
        for (int r = 0; r < 4; r++) {
            int row = m0 + wave * 16 + quad * 4 + r;
            if (row < M) {
                float v = acc3[nt][r] + bv;
                if (FINAL) outF[(size_t)row * 64 + n] = v;
                else       Pout[(size_t)row * 128 + n] = f2bf(v);
            }
        }
    }

    // tail: zero next layer's agg buffer (fused, replaces hipMemsetAsync)
    if (aggZ) {
        const int total = N_NODES * 64 / 4;   // float4 count
        floatx4 z = {0, 0, 0, 0};
        for (int i = blockIdx.x * 256 + tid; i < total; i += gridDim.x * 256)
            ((floatx4*)aggZ)[i] = z;
    }
}

// ---------------------------------------------------------------------------
// Fused embedding: h1 = h0 @ W_in + b_in, P0 = h1 @ W1'[0]; ONE barrier.
// Tail: zero agg buffer for layer 0.
// ---------------------------------------------------------------------------
__global__ __launch_bounds__(256) void embed_fused_k(
    const unsigned short* __restrict__ h0bf, const unsigned short* __restrict__ Win,
    const float* __restrict__ b_in, const unsigned short* __restrict__ W1,
    const float* __restrict__ biasP, float* __restrict__ hF,
    unsigned short* __restrict__ hB, unsigned short* __restrict__ Pout,
    float* __restrict__ aggZ, int M)
{
    __shared__ unsigned short S[64 * 136];
    const int tid = threadIdx.x;
    const int m0 = blockIdx.x * 64;
    const int wave = tid >> 6;
    const int lane = tid & 63;
    const int lrow = lane & 15;
    const int quad = lane >> 4;

    for (int t = tid; t < 64 * 8; t += 256) {
        int rr = t >> 3, c = t & 7;
        int row = m0 + rr;
        uintx4 val = {0, 0, 0, 0};
        if (row < M) val = *(const uintx4*)(h0bf + (size_t)row * 64 + c * 8);
        *(uintx4*)(&S[rr * 136 + c * 8]) = val;
    }
    __syncthreads();   // the only barrier

    floatx4 acc[8];
    #pragma unroll
    for (int i = 0; i < 8; i++) acc[i] = (floatx4){0, 0, 0, 0};
    {
        const unsigned short* arow = &S[(wave * 16 + lrow) * 136];
        #pragma unroll
        for (int kt = 0; kt < 2; kt++) {
            short8 afrag = *(const short8*)(arow + kt * 32 + quad * 8);
            int kb = kt * 4 + quad;
            #pragma unroll
            for (int nt = 0; nt < 8; nt++) {
                short8 bfrag = *(const short8*)(Win + (size_t)(kb * 128 + nt * 16 + lrow) * 8);
                acc[nt] = __builtin_amdgcn_mfma_f32_16x16x32_bf16(afrag, bfrag, acc[nt], 0, 0, 0);
            }
        }
    }

    #pragma unroll
    for (int nt = 0; nt < 8; nt++) {
        int n = nt * 16 + lrow;
        float bv = b_in[n];
        #pragma unroll
        for (int r = 0; r < 4; r++) {
            int el = wave * 16 + quad * 4 + r;
            int row = m0 + el;
            float v = acc[nt][r] + bv;
            unsigned short vb = f2bf(v);
            S[el * 136 + n] = vb;
            if (row < M) {
                hF[(size_t)row * 128 + n] = v;
                hB[(size_t)row * 128 + n] = vb;
            }
        }
    }

    floatx4 acc3[8];
    #pragma unroll
    for (int i = 0; i < 8; i++) acc3[i] = (floatx4){0, 0, 0, 0};
    {
        const unsigned short* arow = &S[(wave * 16 + lrow) * 136];
        #pragma unroll
        for (int kt = 0; kt < 4; kt++) {
            short8 afrag = *(const short8*)(arow + kt * 32 + quad * 8);
            int kb = kt * 4 + quad;
            #pragma unroll
            for (int nt = 0; nt < 8; nt++) {
                short8 bfrag = *(const short8*)(W1 + (size_t)(kb * 128 + nt * 16 + lrow) * 8);
                acc3[nt] = __builtin_amdgcn_mfma_f32_16x16x32_bf16(afrag, bfrag, acc3[nt], 0, 0, 0);
            }
        }
    }
    #pragma unroll
    for (int nt = 0; nt < 8; nt++) {
        int n = nt * 16 + lrow;
        float bv = biasP[n];
        #pragma unroll
        for (int r = 0; r < 4; r++) {
            int row = m0 + wave * 16 + quad * 4 + r;
            if (row < M) Pout[(size_t)row * 128 + n] = f2bf(acc3[nt][r] + bv);
        }
    }

    if (aggZ) {
        const int total = N_NODES * 64 / 4;
        floatx4 z = {0, 0, 0, 0};
        for (int i = blockIdx.x * 256 + tid; i < total; i += gridDim.x * 256)
            ((floatx4*)aggZ)[i] = z;
    }
}

// ---------------------------------------------------------------------------
extern "C" void kernel_launch(void* const* d_in, const int* in_sizes, int n_in,
                              void* d_out, int out_size, void* d_ws, size_t ws_size,
                              hipStream_t stream) {
    const float* h0   = (const float*)d_in[0];
    const int*   edges= (const int*)d_in[1];
    const float* W_in = (const float*)d_in[2];
    const float* b_in = (const float*)d_in[3];
    const float* eW1  = (const float*)d_in[4];
    const float* eb1  = (const float*)d_in[5];
    const float* eW2  = (const float*)d_in[6];
    const float* eb2  = (const float*)d_in[7];
    const float* nW1  = (const float*)d_in[8];
    const float* nb1  = (const float*)d_in[9];
    const float* nW2  = (const float*)d_in[10];
    const float* nb2  = (const float*)d_in[11];
    const float* W_out= (const float*)d_in[12];
    const float* b_out= (const float*)d_in[13];
    float* out = (float*)d_out;

    const int E = in_sizes[1] / 2;      // 800000
    const int* erow = edges;
    const int* ecol = edges + E;

    char* ws = (char*)d_ws;
    unsigned short* hbf  = (unsigned short*)(ws + 0);            // 12,800,000
    float*          hbufF= (float*)(ws + 12800000);              // 25,600,000
    unsigned short* P    = (unsigned short*)(ws + 38400000);     // 12,800,000
    float*          aggA = (float*)(ws + 51200000);              // 12,800,000
    float*          aggB = (float*)(ws + 64000000);              // 12,800,000
    unsigned short* h0bf = (unsigned short*)(ws + 76800000);     //  6,400,000 (start only)
    int*            rowS = (int*)(ws + 76800000);                //  3,200,000 (aliases h0bf)
    int*            colS = (int*)(ws + 80000000);                //  3,200,000
    float*          biasP= (float*)(ws + 83200000);              //  2,048
    unsigned short* Winp = (unsigned short*)(ws + 83202048);     // 16,384
    unsigned short* Woutp= (unsigned short*)(ws + 83218432);     // 16,384
    unsigned short* W1p  = (unsigned short*)(ws + 83234816);     // 131,072
    unsigned short* eW2p = (unsigned short*)(ws + 83365888);     // 32,768
    unsigned short* nW1p = (unsigned short*)(ws + 83398656);     // 196,608
    unsigned short* nW2p = (unsigned short*)(ws + 83595264);     // 131,072
    int*            counts=(int*)(ws + 83726336);                // 200,000
    int*            cursor=(int*)(ws + 83926336);                // 200,000
    int*            bsum = (int*)(ws + 84126336);                // 256

    const int gemm_grid = (N_NODES + 63) / 64;    // 782
    const int edge_grid = (E + 63) / 64;          // 12500
    const int pack_grid = (int)((PACK_TOTAL + 255) / 256);
    const int nb = (N_NODES + 1023) / 1024;       // 49

    pack_kernel<<<pack_grid, 256, 0, stream>>>(h0, W_in, W_out, eW1, eb1, eW2,
                                               nW1, nW2, h0bf, Winp, Woutp, W1p,
                                               eW2p, nW1p, nW2p, biasP);

    // h1 = h0 @ W_in + b_in; P0 = h1 @ W1'[0]; zero aggA for layer 0
    embed_fused_k<<<gemm_grid, 256, 0, stream>>>(
        h0bf, Winp, b_in, W1p, biasP, hbufF, hbf, P, aggA, N_NODES);

    // CSR build
    hipMemsetAsync(counts, 0, (size_t)N_NODES * 4, stream);
    hist_k<<<(E + 255) / 256, 256, 0, stream>>>(erow, counts, E);
    scan1_k<<<nb, 1024, 0, stream>>>(counts, cursor, bsum, N_NODES);
    scan2_k<<<1, 64, 0, stream>>>(bsum, nb);
    scan3_k<<<nb, 1024, 0, stream>>>(cursor, bsum, N_NODES);
    scatter_k<<<(E + 255) / 256, 256, 0, stream>>>(erow, ecol, cursor, rowS, colS, E);

    float* aggBuf[2] = { aggA, aggB };
    for (int l = 0; l < 4; l++) {
        float* aggCur = aggBuf[l & 1];
        float* aggNext = aggBuf[(l + 1) & 1];
        edge_fused_k<<<edge_grid, 256, 0, stream>>>(
            rowS, colS, P, eW2p + (size_t)l * SE2, eb2 + (size_t)l * 64, aggCur, E);
        if (l < 3) {
            node_fused_k<0><<<gemm_grid, 256, 0, stream>>>(
                hbf, aggCur, nW1p + (size_t)l * SN1, nb1 + (size_t)l * 128,
                nW2p + (size_t)l * SN2, nb2 + (size_t)l * 128,
                W1p + (size_t)(l + 1) * SW1, biasP + (size_t)(l + 1) * 128,
                hbufF, hbf, P, nullptr, aggNext, N_NODES);
        } else {
            node_fused_k<1><<<gemm_grid, 256, 0, stream>>>(
                hbf, aggCur, nW1p + (size_t)l * SN1, nb1 + (size_t)l * 128,
                nW2p + (size_t)l * SN2, nb2 + (size_t)l * 128,
                Woutp, b_out, hbufF, hbf, nullptr, out, nullptr, N_NODES);
        }
    }
}

// Round 5
// 555.113 us; speedup vs baseline: 1.2516x; 1.2516x over previous
//
#include <hip/hip_runtime.h>
#include <hip/hip_bf16.h>
#include <cstdint>
#include <cstddef>

#define N_NODES 50000
#define N_EDGES 800000
#define NR      50048    // N_NODES rounded up (hFT row stride, floats)

typedef __attribute__((ext_vector_type(8))) short short8;
typedef __attribute__((ext_vector_type(4))) float floatx4;
typedef __attribute__((ext_vector_type(4))) unsigned int uintx4;

__device__ inline float bf2f(unsigned short u) {
    union { unsigned int i; float f; } v; v.i = ((unsigned int)u) << 16; return v.f;
}
__device__ inline unsigned short f2bf(float f) {
    union { float f; unsigned int i; } v; v.f = f;
    unsigned int u = v.i;
    return (unsigned short)((u + 0x7FFFu + ((u >> 16) & 1u)) >> 16);
}
// silu via v_rcp_f32 (1 ulp) instead of IEEE divide
__device__ inline float silu_f(float x) {
    float e = __expf(-x);
    return x * __builtin_amdgcn_rcpf(1.0f + e);
}

// ---------------------------------------------------------------------------
// Pack kernel + fused CSR histogram.
// B-fragment order: Bp[(kb*NOUT + n)*8 + i] = B[(kb*8+i)*NOUT + n]
// ---------------------------------------------------------------------------
__device__ inline void pack_std(const float* __restrict__ src,
                                unsigned short* __restrict__ dst,
                                int NOUT, long j) {
    int i = (int)(j & 7);
    long rest = j >> 3;
    int n = (int)(rest % NOUT);
    int kb = (int)(rest / NOUT);
    dst[j] = f2bf(src[(long)(kb * 8 + i) * NOUT + n]);
}

#define NH0   (N_NODES * 64L)
#define SW_IN 8192L
#define SW_OUT 8192L
#define SW1   16384L
#define SE2   4096L
#define SN1   24576L
#define SN2   16384L
#define SB    128L
#define PERL  (SW1 + SE2 + SN1 + SN2 + SB)
#define PACK_TOTAL (NH0 + SW_IN + SW_OUT + 4 * PERL)
#define PACK_TOTAL2 (PACK_TOTAL + N_EDGES)

__global__ __launch_bounds__(256) void pack_kernel(
    const float* __restrict__ h0, const float* __restrict__ W_in,
    const float* __restrict__ W_out, const float* __restrict__ eW1,
    const float* __restrict__ eb1, const float* __restrict__ eW2,
    const float* __restrict__ nW1, const float* __restrict__ nW2,
    unsigned short* __restrict__ h0bf, unsigned short* __restrict__ Winp,
    unsigned short* __restrict__ Woutp, unsigned short* __restrict__ W1p,
    unsigned short* __restrict__ eW2p, unsigned short* __restrict__ nW1p,
    unsigned short* __restrict__ nW2p, float* __restrict__ biasP,
    const int* __restrict__ erow, int* __restrict__ counts)
{
    long idx = (long)blockIdx.x * 256 + threadIdx.x;
    if (idx >= PACK_TOTAL2) return;
    if (idx >= PACK_TOTAL) {                 // fused CSR histogram
        atomicAdd(&counts[erow[idx - PACK_TOTAL]], 1);
        return;
    }
    long j = idx;
    if (j < NH0) { h0bf[j] = f2bf(h0[j]); return; }
    j -= NH0;
    if (j < SW_IN) { pack_std(W_in, Winp, 128, j); return; }
    j -= SW_IN;
    if (j < SW_OUT) { pack_std(W_out, Woutp, 64, j); return; }
    j -= SW_OUT;
    int l = (int)(j / PERL);
    long r = j % PERL;
    if (r < SW1) {
        int i = (int)(r & 7);
        int n = (int)((r >> 3) & 127);
        int kb = (int)(r >> 10);
        int k = kb * 8 + i;
        const float* w = eW1 + (long)l * 256 * 64;
        float v = (n < 64) ? w[(long)k * 64 + n] : w[(long)(128 + k) * 64 + (n - 64)];
        W1p[(long)l * SW1 + r] = f2bf(v);
        return;
    }
    r -= SW1;
    if (r < SE2) { pack_std(eW2 + (long)l * 4096, eW2p + (long)l * SE2, 64, r); return; }
    r -= SE2;
    if (r < SN1) { pack_std(nW1 + (long)l * 24576, nW1p + (long)l * SN1, 128, r); return; }
    r -= SN1;
    if (r < SN2) { pack_std(nW2 + (long)l * 16384, nW2p + (long)l * SN2, 128, r); return; }
    r -= SN2;
    biasP[(long)l * 128 + r] = (r < 64) ? eb1[(long)l * 64 + r] : 0.0f;
}

// ---------------------------------------------------------------------------
// CSR scan/scatter
// ---------------------------------------------------------------------------
__global__ __launch_bounds__(1024) void scan1_k(const int* __restrict__ counts,
                                                int* __restrict__ cursor,
                                                int* __restrict__ bsum, int n) {
    __shared__ int buf[1024];
    int i = blockIdx.x * 1024 + threadIdx.x;
    int v = (i < n) ? counts[i] : 0;
    buf[threadIdx.x] = v;
    __syncthreads();
    #pragma unroll
    for (int off = 1; off < 1024; off <<= 1) {
        int t = (threadIdx.x >= off) ? buf[threadIdx.x - off] : 0;
        __syncthreads();
        buf[threadIdx.x] += t;
        __syncthreads();
    }
    if (i < n) cursor[i] = buf[threadIdx.x] - v;
    if (threadIdx.x == 1023) bsum[blockIdx.x] = buf[1023];
}

__global__ __launch_bounds__(64) void scan2_k(int* __restrict__ bsum, int nb) {
    __shared__ int b[64];
    int tid = threadIdx.x;
    int v = (tid < nb) ? bsum[tid] : 0;
    b[tid] = v;
    __syncthreads();
    #pragma unroll
    for (int off = 1; off < 64; off <<= 1) {
        int t = (tid >= off) ? b[tid - off] : 0;
        __syncthreads();
        b[tid] += t;
        __syncthreads();
    }
    if (tid < nb) bsum[tid] = b[tid] - v;
}

__global__ __launch_bounds__(1024) void scan3_k(int* __restrict__ cursor,
                                                const int* __restrict__ bsum, int n) {
    int i = blockIdx.x * 1024 + threadIdx.x;
    if (i < n) cursor[i] += bsum[blockIdx.x];
}

__global__ __launch_bounds__(256) void scatter_k(const int* __restrict__ erow,
                                                 const int* __restrict__ ecol,
                                                 int* __restrict__ cursor,
                                                 int* __restrict__ rowS,
                                                 int* __restrict__ colS, int E) {
    int e = blockIdx.x * 256 + threadIdx.x;
    if (e < E) {
        int r = erow[e];
        int s = atomicAdd(&cursor[r], 1);
        rowS[s] = r;
        colS[s] = ecol[e];
    }
}

// ---------------------------------------------------------------------------
// Fused edge + block-segmented aggregate over CSR-sorted edges (R3 version).
// ---------------------------------------------------------------------------
__global__ __launch_bounds__(256) void edge_fused_k(
    const int* __restrict__ rowS, const int* __restrict__ colS,
    const unsigned short* __restrict__ P,    // [N,128]: 0..63 top(+b1), 64..127 bot
    const unsigned short* __restrict__ Bp,   // eW2 frag order
    const float* __restrict__ b2, float* __restrict__ agg, int E)
{
    __shared__ unsigned short Ms[64 * 72];
    __shared__ float M2s[64 * 68];
    __shared__ int ridS[64];
    __shared__ short segStartS[66];
    __shared__ int nsegS;
    const int tid = threadIdx.x;
    const int e0 = blockIdx.x * 64;

    // stage 1: gather endpoints, silu(Ptop[row]+Pbot[col]) -> Ms (bf16)
    {
        int el = tid >> 2;
        int part = tid & 3;
        int s = e0 + el;
        if (s < E) {
            int rr = rowS[s], cc = colS[s];
            if (part == 0) ridS[el] = rr;
            const uintx4* pt = (const uintx4*)(P + (size_t)rr * 128 + part * 16);
            const uintx4* pb = (const uintx4*)(P + (size_t)cc * 128 + 64 + part * 16);
            #pragma unroll
            for (int h = 0; h < 2; h++) {
                uintx4 a = pt[h], b = pb[h];
                const unsigned short* au = (const unsigned short*)&a;
                const unsigned short* bu = (const unsigned short*)&b;
                unsigned short o[8];
                #pragma unroll
                for (int i = 0; i < 8; i++) {
                    float x = bf2f(au[i]) + bf2f(bu[i]);
                    o[i] = f2bf(silu_f(x));
                }
                *(uintx4*)(&Ms[el * 72 + part * 16 + h * 8]) = *(const uintx4*)o;
            }
        } else if (part == 0) {
            ridS[el] = -1;
        }
    }
    __syncthreads();

    // stage 2: m2 = Ms @ eW2 via MFMA
    const int wave = tid >> 6;
    const int lane = tid & 63;
    const int lrow = lane & 15;
    const int quad = lane >> 4;

    floatx4 acc[4];
    #pragma unroll
    for (int i = 0; i < 4; i++) acc[i] = (floatx4){0, 0, 0, 0};

    const unsigned short* arow = &Ms[(wave * 16 + lrow) * 72];
    #pragma unroll
    for (int kt = 0; kt < 2; kt++) {
        short8 afrag = *(const short8*)(arow + kt * 32 + quad * 8);
        int kb = kt * 4 + quad;
        #pragma unroll
        for (int nt = 0; nt < 4; nt++) {
            short8 bfrag = *(const short8*)(Bp + (size_t)(kb * 64 + nt * 16 + lrow) * 8);
            acc[nt] = __builtin_amdgcn_mfma_f32_16x16x32_bf16(afrag, bfrag, acc[nt], 0, 0, 0);
        }
    }

    // stage 3: silu(m2 + b2) -> M2s (fp32)
    #pragma unroll
    for (int nt = 0; nt < 4; nt++) {
        int n = nt * 16 + lrow;
        float bv = b2[n];
        #pragma unroll
        for (int r = 0; r < 4; r++) {
            int el = wave * 16 + quad * 4 + r;
            M2s[el * 68 + n] = silu_f(acc[nt][r] + bv);
        }
    }

    // segment detection (wave 0)
    if (tid < 64) {
        bool st = (ridS[tid] >= 0) && (tid == 0 || ridS[tid] != ridS[tid - 1]);
        unsigned long long m = __ballot(st);
        if (st) {
            int pos = __popcll(m & ((1ull << tid) - 1));
            segStartS[pos] = (short)tid;
        }
        if (tid == 0) {
            int ns = __popcll(m);
            nsegS = ns;
            int nvalid = E - e0;
            if (nvalid > 64) nvalid = 64;
            segStartS[ns] = (short)nvalid;
        }
    }
    __syncthreads();

    // stage 4: segmented reduce; interior segments plain-store, edges atomic
    {
        int f = tid & 63;
        int g = tid >> 6;
        int ns = nsegS;
        for (int j = g; j < ns; j += 4) {
            int a = segStartS[j], b = segStartS[j + 1];
            float s = 0.0f;
            for (int el = a; el < b; el++) s += M2s[el * 68 + f];
            int rv = ridS[a];
            if (j == 0 || j == ns - 1)
                atomicAdd(&agg[(size_t)rv * 64 + f], s);
            else
                agg[(size_t)rv * 64 + f] = s;
        }
    }
}

// ---------------------------------------------------------------------------
// Fused node-side chain. Residual in TRANSPOSED fp32 hFT[128][NR]:
// MFMA C-layout rows are contiguous there -> float4 loads/stores.
// Epilogue results round-trip through LDS and are stored cooperatively as
// dwordx4. Two barriers total.
//   t     = silu([h | agg] @ nW1 + nb1)      (K=192 -> 128)
//   h_new = hFT + t @ nW2 + nb2
//   FINAL=0: P = h_new @ W1'[l+1] ; FINAL=1: out = h_new @ W_out
// ---------------------------------------------------------------------------
#define SROW 264
template<int FINAL>
__global__ __launch_bounds__(256) void node_fused_k(
    const unsigned short* __restrict__ hbf, const float* __restrict__ agg,
    const unsigned short* __restrict__ W1, const float* __restrict__ b1,
    const unsigned short* __restrict__ W2, const float* __restrict__ b2,
    const unsigned short* __restrict__ B3, const float* __restrict__ bias3,
    float* __restrict__ hFT, unsigned short* __restrict__ hB,
    unsigned short* __restrict__ Pout, float* __restrict__ outF, int M)
{
    __shared__ unsigned short S[64 * SROW];
    const int tid = threadIdx.x;
    const int m0 = blockIdx.x * 64;
    const int wave = tid >> 6;
    const int lane = tid & 63;
    const int lrow = lane & 15;
    const int quad = lane >> 4;
    const int row0 = m0 + wave * 16 + quad * 4;   // lane's 4 C-rows

    // prefetch residual: 8 x dwordx4 from transposed hFT (in-bounds via NR pad)
    floatx4 res4[8];
    #pragma unroll
    for (int nt = 0; nt < 8; nt++)
        res4[nt] = *(const floatx4*)(hFT + (size_t)(nt * 16 + lrow) * NR + row0);

    // staging: [h(128 bf16) | agg(64 fp32->bf16)] -> S cols 0..191
    for (int t = tid; t < 64 * 24; t += 256) {
        int rr = t / 24, c = t % 24;
        int row = m0 + rr;
        uintx4 val = {0, 0, 0, 0};
        if (row < M) {
            if (c < 16) {
                val = *(const uintx4*)(hbf + (size_t)row * 128 + c * 8);
            } else {
                const floatx4* s4 = (const floatx4*)(agg + (size_t)row * 64 + (c - 16) * 8);
                floatx4 f0 = s4[0], f1 = s4[1];
                unsigned short tmp[8];
                #pragma unroll
                for (int i = 0; i < 4; i++) { tmp[i] = f2bf(f0[i]); tmp[4 + i] = f2bf(f1[i]); }
                val = *(const uintx4*)tmp;
            }
        }
        *(uintx4*)(&S[rr * SROW + c * 8]) = val;
    }
    __syncthreads();   // barrier 1

    // ---- phase A MFMA: K=192, NOUT=128 ----
    floatx4 acc[8];
    #pragma unroll
    for (int i = 0; i < 8; i++) acc[i] = (floatx4){0, 0, 0, 0};
    {
        const unsigned short* arow = &S[(wave * 16 + lrow) * SROW];
        #pragma unroll
        for (int kt = 0; kt < 6; kt++) {
            short8 afrag = *(const short8*)(arow + kt * 32 + quad * 8);
            int kb = kt * 4 + quad;
            #pragma unroll
            for (int nt = 0; nt < 8; nt++) {
                short8 bfrag = *(const short8*)(W1 + (size_t)(kb * 128 + nt * 16 + lrow) * 8);
                acc[nt] = __builtin_amdgcn_mfma_f32_16x16x32_bf16(afrag, bfrag, acc[nt], 0, 0, 0);
            }
        }
    }

    // epilogue A: t -> own S rows, cols 0..127 (wave-private; no barrier)
    #pragma unroll
    for (int nt = 0; nt < 8; nt++) {
        int n = nt * 16 + lrow;
        float bv = b1[n];
        #pragma unroll
        for (int r = 0; r < 4; r++) {
            int el = wave * 16 + quad * 4 + r;
            S[el * SROW + n] = f2bf(silu_f(acc[nt][r] + bv));
        }
    }

    // ---- phase B MFMA: K=128, NOUT=128 ----
    floatx4 acc2[8];
    #pragma unroll
    for (int i = 0; i < 8; i++) acc2[i] = (floatx4){0, 0, 0, 0};
    {
        const unsigned short* arow = &S[(wave * 16 + lrow) * SROW];
        #pragma unroll
        for (int kt = 0; kt < 4; kt++) {
            short8 afrag = *(const short8*)(arow + kt * 32 + quad * 8);
            int kb = kt * 4 + quad;
            #pragma unroll
            for (int nt = 0; nt < 8; nt++) {
                short8 bfrag = *(const short8*)(W2 + (size_t)(kb * 128 + nt * 16 + lrow) * 8);
                acc2[nt] = __builtin_amdgcn_mfma_f32_16x16x32_bf16(afrag, bfrag, acc2[nt], 0, 0, 0);
            }
        }
    }

    // epilogue B: h_new = acc2 + b2 + res4 -> S (bf16) + hFT (float4)
    #pragma unroll
    for (int nt = 0; nt < 8; nt++) {
        int n = nt * 16 + lrow;
        float bv = b2[n];
        floatx4 v4;
        #pragma unroll
        for (int r = 0; r < 4; r++) {
            int el = wave * 16 + quad * 4 + r;
            float v = acc2[nt][r] + bv + res4[nt][r];
            v4[r] = v;
            S[el * SROW + n] = f2bf(v);
        }
        if (!FINAL && row0 < M)
            *(floatx4*)(hFT + (size_t)n * NR + row0) = v4;
    }

    // ---- phase C MFMA: K=128 -> P (128) or out (64) ----
    constexpr int NT3 = FINAL ? 4 : 8;
    constexpr int NO3 = FINAL ? 64 : 128;
    floatx4 acc3[NT3];
    #pragma unroll
    for (int i = 0; i < NT3; i++) acc3[i] = (floatx4){0, 0, 0, 0};
    {
        const unsigned short* arow = &S[(wave * 16 + lrow) * SROW];
        #pragma unroll
        for (int kt = 0; kt < 4; kt++) {
            short8 afrag = *(const short8*)(arow + kt * 32 + quad * 8);
            int kb = kt * 4 + quad;
            #pragma unroll
            for (int nt = 0; nt < NT3; nt++) {
                short8 bfrag = *(const short8*)(B3 + (size_t)(kb * NO3 + nt * 16 + lrow) * 8);
                acc3[nt] = __builtin_amdgcn_mfma_f32_16x16x32_bf16(afrag, bfrag, acc3[nt], 0, 0, 0);
            }
        }
    }
    // epilogue C -> S cols 128..255 (bf16 P) or fp32 out region
    #pragma unroll
    for (int nt = 0; nt < NT3; nt++) {
        int n = nt * 16 + lrow;
        float bv = bias3[n];
        #pragma unroll
        for (int r = 0; r < 4; r++) {
            int el = wave * 16 + quad * 4 + r;
            float v = acc3[nt][r] + bv;
            if (FINAL) ((float*)(&S[el * SROW + 128]))[n] = v;
            else       S[el * SROW + 128 + n] = f2bf(v);
        }
    }
    __syncthreads();   // barrier 2

    // cooperative wide stores
    if (FINAL) {
        // out[row][0..63] fp32 from S float region
        for (int t = tid; t < 64 * 16; t += 256) {
            int rr = t / 16, c = t % 16;
            int row = m0 + rr;
            if (row < M)
                *(floatx4*)(outF + (size_t)row * 64 + c * 4) =
                    *(const floatx4*)((const float*)(&S[rr * SROW + 128]) + c * 4);
        }
    } else {
        // hB (cols 0..127) and P (cols 128..255) as dwordx4
        for (int t = tid; t < 64 * 32; t += 256) {
            int rr = t / 32, c = t % 32;
            int row = m0 + rr;
            if (row < M) {
                if (c < 16)
                    *(uintx4*)(hB + (size_t)row * 128 + c * 8) =
                        *(const uintx4*)(&S[rr * SROW + c * 8]);
                else
                    *(uintx4*)(Pout + (size_t)row * 128 + (c - 16) * 8) =
                        *(const uintx4*)(&S[rr * SROW + 128 + (c - 16) * 8]);
            }
        }
    }
}

// ---------------------------------------------------------------------------
// Fused embedding: h1 = h0 @ W_in + b_in -> hFT/hB, P0 = h1 @ W1'[0]
// ---------------------------------------------------------------------------
__global__ __launch_bounds__(256) void embed_fused_k(
    const unsigned short* __restrict__ h0bf, const unsigned short* __restrict__ Win,
    const float* __restrict__ b_in, const unsigned short* __restrict__ W1,
    const float* __restrict__ biasP, float* __restrict__ hFT,
    unsigned short* __restrict__ hB, unsigned short* __restrict__ Pout, int M)
{
    __shared__ unsigned short S[64 * SROW];
    const int tid = threadIdx.x;
    const int m0 = blockIdx.x * 64;
    const int wave = tid >> 6;
    const int lane = tid & 63;
    const int lrow = lane & 15;
    const int quad = lane >> 4;
    const int row0 = m0 + wave * 16 + quad * 4;

    for (int t = tid; t < 64 * 8; t += 256) {
        int rr = t >> 3, c = t & 7;
        int row = m0 + rr;
        uintx4 val = {0, 0, 0, 0};
        if (row < M) val = *(const uintx4*)(h0bf + (size_t)row * 64 + c * 8);
        *(uintx4*)(&S[rr * SROW + c * 8]) = val;
    }
    __syncthreads();   // barrier 1

    floatx4 acc[8];
    #pragma unroll
    for (int i = 0; i < 8; i++) acc[i] = (floatx4){0, 0, 0, 0};
    {
        const unsigned short* arow = &S[(wave * 16 + lrow) * SROW];
        #pragma unroll
        for (int kt = 0; kt < 2; kt++) {
            short8 afrag = *(const short8*)(arow + kt * 32 + quad * 8);
            int kb = kt * 4 + quad;
            #pragma unroll
            for (int nt = 0; nt < 8; nt++) {
                short8 bfrag = *(const short8*)(Win + (size_t)(kb * 128 + nt * 16 + lrow) * 8);
                acc[nt] = __builtin_amdgcn_mfma_f32_16x16x32_bf16(afrag, bfrag, acc[nt], 0, 0, 0);
            }
        }
    }

    // epilogue: h1 -> S cols 0..127 (bf16) + hFT float4 (wave-private rows)
    #pragma unroll
    for (int nt = 0; nt < 8; nt++) {
        int n = nt * 16 + lrow;
        float bv = b_in[n];
        floatx4 v4;
        #pragma unroll
        for (int r = 0; r < 4; r++) {
            int el = wave * 16 + quad * 4 + r;
            float v = acc[nt][r] + bv;
            v4[r] = v;
            S[el * SROW + n] = f2bf(v);
        }
        if (row0 < M)
            *(floatx4*)(hFT + (size_t)n * NR + row0) = v4;
    }

    floatx4 acc3[8];
    #pragma unroll
    for (int i = 0; i < 8; i++) acc3[i] = (floatx4){0, 0, 0, 0};
    {
        const unsigned short* arow = &S[(wave * 16 + lrow) * SROW];
        #pragma unroll
        for (int kt = 0; kt < 4; kt++) {
            short8 afrag = *(const short8*)(arow + kt * 32 + quad * 8);
            int kb = kt * 4 + quad;
            #pragma unroll
            for (int nt = 0; nt < 8; nt++) {
                short8 bfrag = *(const short8*)(W1 + (size_t)(kb * 128 + nt * 16 + lrow) * 8);
                acc3[nt] = __builtin_amdgcn_mfma_f32_16x16x32_bf16(afrag, bfrag, acc3[nt], 0, 0, 0);
            }
        }
    }
    #pragma unroll
    for (int nt = 0; nt < 8; nt++) {
        int n = nt * 16 + lrow;
        float bv = biasP[n];
        #pragma unroll
        for (int r = 0; r < 4; r++) {
            int el = wave * 16 + quad * 4 + r;
            S[el * SROW + 128 + n] = f2bf(acc3[nt][r] + bv);
        }
    }
    __syncthreads();   // barrier 2

    for (int t = tid; t < 64 * 32; t += 256) {
        int rr = t / 32, c = t % 32;
        int row = m0 + rr;
        if (row < M) {
            if (c < 16)
                *(uintx4*)(hB + (size_t)row * 128 + c * 8) =
                    *(const uintx4*)(&S[rr * SROW + c * 8]);
            else
                *(uintx4*)(Pout + (size_t)row * 128 + (c - 16) * 8) =
                    *(const uintx4*)(&S[rr * SROW + 128 + (c - 16) * 8]);
        }
    }
}

// ---------------------------------------------------------------------------
extern "C" void kernel_launch(void* const* d_in, const int* in_sizes, int n_in,
                              void* d_out, int out_size, void* d_ws, size_t ws_size,
                              hipStream_t stream) {
    const float* h0   = (const float*)d_in[0];
    const int*   edges= (const int*)d_in[1];
    const float* W_in = (const float*)d_in[2];
    const float* b_in = (const float*)d_in[3];
    const float* eW1  = (const float*)d_in[4];
    const float* eb1  = (const float*)d_in[5];
    const float* eW2  = (const float*)d_in[6];
    const float* eb2  = (const float*)d_in[7];
    const float* nW1  = (const float*)d_in[8];
    const float* nb1  = (const float*)d_in[9];
    const float* nW2  = (const float*)d_in[10];
    const float* nb2  = (const float*)d_in[11];
    const float* W_out= (const float*)d_in[12];
    const float* b_out= (const float*)d_in[13];
    float* out = (float*)d_out;

    const int E = in_sizes[1] / 2;      // 800000
    const int* erow = edges;
    const int* ecol = edges + E;

    char* ws = (char*)d_ws;
    unsigned short* hbf  = (unsigned short*)(ws + 0);            // 12,800,000
    float*          hFT  = (float*)(ws + 12800000);              // 25,624,576 (128 x NR fp32)
    unsigned short* P    = (unsigned short*)(ws + 38424576);     // 12,800,000
    float*          agg  = (float*)(ws + 51224576);              // 12,800,000
    unsigned short* h0bf = (unsigned short*)(ws + 76824576);     //  6,400,000 (start only)
    int*            rowS = (int*)(ws + 76824576);                //  3,200,000 (aliases h0bf)
    int*            colS = (int*)(ws + 80024576);                //  3,200,000
    float*          biasP= (float*)(ws + 83224576);              //  2,048
    unsigned short* Winp = (unsigned short*)(ws + 83226624);     // 16,384
    unsigned short* Woutp= (unsigned short*)(ws + 83243008);     // 16,384
    unsigned short* W1p  = (unsigned short*)(ws + 83259392);     // 131,072
    unsigned short* eW2p = (unsigned short*)(ws + 83390464);     // 32,768
    unsigned short* nW1p = (unsigned short*)(ws + 83423232);     // 196,608
    unsigned short* nW2p = (unsigned short*)(ws + 83619840);     // 131,072
    int*            counts=(int*)(ws + 83750912);                // 200,000
    int*            cursor=(int*)(ws + 83950912);                // 200,000
    int*            bsum = (int*)(ws + 84150912);                // 256

    const int gemm_grid = (N_NODES + 63) / 64;    // 782
    const int edge_grid = (E + 63) / 64;          // 12500
    const int pack_grid = (int)((PACK_TOTAL2 + 255) / 256);
    const int nb = (N_NODES + 1023) / 1024;       // 49

    hipMemsetAsync(counts, 0, (size_t)N_NODES * 4, stream);
    pack_kernel<<<pack_grid, 256, 0, stream>>>(h0, W_in, W_out, eW1, eb1, eW2,
                                               nW1, nW2, h0bf, Winp, Woutp, W1p,
                                               eW2p, nW1p, nW2p, biasP,
                                               erow, counts);

    // h1 = h0 @ W_in + b_in; P0 = h1 @ W1'[0]  (reads h0bf before scatter reuse)
    embed_fused_k<<<gemm_grid, 256, 0, stream>>>(
        h0bf, Winp, b_in, W1p, biasP, hFT, hbf, P, N_NODES);

    scan1_k<<<nb, 1024, 0, stream>>>(counts, cursor, bsum, N_NODES);
    scan2_k<<<1, 64, 0, stream>>>(bsum, nb);
    scan3_k<<<nb, 1024, 0, stream>>>(cursor, bsum, N_NODES);
    scatter_k<<<(E + 255) / 256, 256, 0, stream>>>(erow, ecol, cursor, rowS, colS, E);

    for (int l = 0; l < 4; l++) {
        hipMemsetAsync(agg, 0, (size_t)N_NODES * 64 * 4, stream);
        edge_fused_k<<<edge_grid, 256, 0, stream>>>(
            rowS, colS, P, eW2p + (size_t)l * SE2, eb2 + (size_t)l * 64, agg, E);
        if (l < 3) {
            node_fused_k<0><<<gemm_grid, 256, 0, stream>>>(
                hbf, agg, nW1p + (size_t)l * SN1, nb1 + (size_t)l * 128,
                nW2p + (size_t)l * SN2, nb2 + (size_t)l * 128,
                W1p + (size_t)(l + 1) * SW1, biasP + (size_t)(l + 1) * 128,
                hFT, hbf, P, nullptr, N_NODES);
        } else {
            node_fused_k<1><<<gemm_grid, 256, 0, stream>>>(
                hbf, agg, nW1p + (size_t)l * SN1, nb1 + (size_t)l * 128,
                nW2p + (size_t)l * SN2, nb2 + (size_t)l * 128,
                Woutp, b_out, hFT, hbf, nullptr, out, N_NODES);
        }
    }
}

// Round 6
// 528.805 us; speedup vs baseline: 1.3139x; 1.0498x over previous
//
#include <hip/hip_runtime.h>
#include <hip/hip_bf16.h>
#include <cstdint>
#include <cstddef>

#define N_NODES 50000
#define N_EDGES 800000
#define NR      50048    // N_NODES rounded up (hFT row stride, floats)

typedef __attribute__((ext_vector_type(8))) short short8;
typedef __attribute__((ext_vector_type(4))) float floatx4;
typedef __attribute__((ext_vector_type(4))) unsigned int uintx4;

__device__ inline float bf2f(unsigned short u) {
    union { unsigned int i; float f; } v; v.i = ((unsigned int)u) << 16; return v.f;
}
__device__ inline unsigned short f2bf(float f) {
    union { float f; unsigned int i; } v; v.f = f;
    unsigned int u = v.i;
    return (unsigned short)((u + 0x7FFFu + ((u >> 16) & 1u)) >> 16);
}
// silu via v_rcp_f32 (1 ulp) instead of IEEE divide
__device__ inline float silu_f(float x) {
    float e = __expf(-x);
    return x * __builtin_amdgcn_rcpf(1.0f + e);
}

// ---------------------------------------------------------------------------
// Pack kernel + fused CSR histogram.
// B-fragment order: Bp[(kb*NOUT + n)*8 + i] = B[(kb*8+i)*NOUT + n]
// ---------------------------------------------------------------------------
__device__ inline void pack_std(const float* __restrict__ src,
                                unsigned short* __restrict__ dst,
                                int NOUT, long j) {
    int i = (int)(j & 7);
    long rest = j >> 3;
    int n = (int)(rest % NOUT);
    int kb = (int)(rest / NOUT);
    dst[j] = f2bf(src[(long)(kb * 8 + i) * NOUT + n]);
}

#define NH0   (N_NODES * 64L)
#define SW_IN 8192L
#define SW_OUT 8192L
#define SW1   16384L
#define SE2   4096L
#define SN1   24576L
#define SN2   16384L
#define SB    128L
#define PERL  (SW1 + SE2 + SN1 + SN2 + SB)
#define PACK_TOTAL (NH0 + SW_IN + SW_OUT + 4 * PERL)
#define PACK_TOTAL2 (PACK_TOTAL + N_EDGES)

__global__ __launch_bounds__(256) void pack_kernel(
    const float* __restrict__ h0, const float* __restrict__ W_in,
    const float* __restrict__ W_out, const float* __restrict__ eW1,
    const float* __restrict__ eb1, const float* __restrict__ eW2,
    const float* __restrict__ nW1, const float* __restrict__ nW2,
    unsigned short* __restrict__ h0bf, unsigned short* __restrict__ Winp,
    unsigned short* __restrict__ Woutp, unsigned short* __restrict__ W1p,
    unsigned short* __restrict__ eW2p, unsigned short* __restrict__ nW1p,
    unsigned short* __restrict__ nW2p, float* __restrict__ biasP,
    const int* __restrict__ erow, int* __restrict__ counts)
{
    long idx = (long)blockIdx.x * 256 + threadIdx.x;
    if (idx >= PACK_TOTAL2) return;
    if (idx >= PACK_TOTAL) {                 // fused CSR histogram
        atomicAdd(&counts[erow[idx - PACK_TOTAL]], 1);
        return;
    }
    long j = idx;
    if (j < NH0) { h0bf[j] = f2bf(h0[j]); return; }
    j -= NH0;
    if (j < SW_IN) { pack_std(W_in, Winp, 128, j); return; }
    j -= SW_IN;
    if (j < SW_OUT) { pack_std(W_out, Woutp, 64, j); return; }
    j -= SW_OUT;
    int l = (int)(j / PERL);
    long r = j % PERL;
    if (r < SW1) {
        int i = (int)(r & 7);
        int n = (int)((r >> 3) & 127);
        int kb = (int)(r >> 10);
        int k = kb * 8 + i;
        const float* w = eW1 + (long)l * 256 * 64;
        float v = (n < 64) ? w[(long)k * 64 + n] : w[(long)(128 + k) * 64 + (n - 64)];
        W1p[(long)l * SW1 + r] = f2bf(v);
        return;
    }
    r -= SW1;
    if (r < SE2) { pack_std(eW2 + (long)l * 4096, eW2p + (long)l * SE2, 64, r); return; }
    r -= SE2;
    if (r < SN1) { pack_std(nW1 + (long)l * 24576, nW1p + (long)l * SN1, 128, r); return; }
    r -= SN1;
    if (r < SN2) { pack_std(nW2 + (long)l * 16384, nW2p + (long)l * SN2, 128, r); return; }
    r -= SN2;
    biasP[(long)l * 128 + r] = (r < 64) ? eb1[(long)l * 64 + r] : 0.0f;
}

// ---------------------------------------------------------------------------
// CSR scan/scatter
// ---------------------------------------------------------------------------
__global__ __launch_bounds__(1024) void scan1_k(const int* __restrict__ counts,
                                                int* __restrict__ cursor,
                                                int* __restrict__ bsum, int n) {
    __shared__ int buf[1024];
    int i = blockIdx.x * 1024 + threadIdx.x;
    int v = (i < n) ? counts[i] : 0;
    buf[threadIdx.x] = v;
    __syncthreads();
    #pragma unroll
    for (int off = 1; off < 1024; off <<= 1) {
        int t = (threadIdx.x >= off) ? buf[threadIdx.x - off] : 0;
        __syncthreads();
        buf[threadIdx.x] += t;
        __syncthreads();
    }
    if (i < n) cursor[i] = buf[threadIdx.x] - v;
    if (threadIdx.x == 1023) bsum[blockIdx.x] = buf[1023];
}

__global__ __launch_bounds__(64) void scan2_k(int* __restrict__ bsum, int nb) {
    __shared__ int b[64];
    int tid = threadIdx.x;
    int v = (tid < nb) ? bsum[tid] : 0;
    b[tid] = v;
    __syncthreads();
    #pragma unroll
    for (int off = 1; off < 64; off <<= 1) {
        int t = (tid >= off) ? b[tid - off] : 0;
        __syncthreads();
        b[tid] += t;
        __syncthreads();
    }
    if (tid < nb) bsum[tid] = b[tid] - v;
}

__global__ __launch_bounds__(1024) void scan3_k(int* __restrict__ cursor,
                                                const int* __restrict__ bsum, int n) {
    int i = blockIdx.x * 1024 + threadIdx.x;
    if (i < n) cursor[i] += bsum[blockIdx.x];
}

// single 8B store per edge: halves dirtied cache lines vs two 4B scatters
__global__ __launch_bounds__(256) void scatter_k(const int* __restrict__ erow,
                                                 const int* __restrict__ ecol,
                                                 int* __restrict__ cursor,
                                                 int2* __restrict__ eidx, int E) {
    int e = blockIdx.x * 256 + threadIdx.x;
    if (e < E) {
        int r = erow[e];
        int s = atomicAdd(&cursor[r], 1);
        eidx[s] = make_int2(r, ecol[e]);
    }
}

// ---------------------------------------------------------------------------
// Fused edge + block-segmented aggregate over CSR-sorted edges.
// v2: A-fragments gathered straight into registers (lane loads exactly its
// own MFMA fragment chunks) -> no Ms LDS, no stage-1 barrier, LDS ~18KB
// -> 8 blocks/CU occupancy. Block-wide segment reduce as in R3.
// ---------------------------------------------------------------------------
__global__ __launch_bounds__(256) void edge_fused_k(
    const int2* __restrict__ eidx,
    const unsigned short* __restrict__ P,    // [N,128]: 0..63 top(+b1), 64..127 bot
    const unsigned short* __restrict__ Bp,   // eW2 frag order
    const float* __restrict__ b2, float* __restrict__ agg, int E)
{
    __shared__ float M2s[64 * 68];
    __shared__ int ridS[64];
    __shared__ short segStartS[66];
    __shared__ int nsegS;
    const int tid = threadIdx.x;
    const int wave = tid >> 6;
    const int lane = tid & 63;
    const int lrow = lane & 15;
    const int quad = lane >> 4;
    const int e0 = blockIdx.x * 64;
    const int el = wave * 16 + lrow;
    const int e = e0 + el;

    // gather + silu directly into A-fragments:
    // lane (w,lrow,quad) owns features {8q..8q+8} (kt=0) and {32+8q..} (kt=1)
    // of edge el = 16w+lrow  (MFMA A layout: A[m=lane&15][k=quad*8+j])
    short8 af0 = {0, 0, 0, 0, 0, 0, 0, 0};
    short8 af1 = af0;
    if (e < E) {
        int2 rc = eidx[e];
        int rr = rc.x, cc = rc.y;
        if (quad == 0) ridS[el] = rr;
        const uintx4* pt = (const uintx4*)(P + (size_t)rr * 128 + quad * 8);
        const uintx4* pb = (const uintx4*)(P + (size_t)cc * 128 + 64 + quad * 8);
        uintx4 t0 = pt[0], t1 = pt[4];       // +32 features = +4 x uintx4
        uintx4 b0 = pb[0], b1 = pb[4];
        const unsigned short* t0u = (const unsigned short*)&t0;
        const unsigned short* t1u = (const unsigned short*)&t1;
        const unsigned short* b0u = (const unsigned short*)&b0;
        const unsigned short* b1u = (const unsigned short*)&b1;
        unsigned short o0[8], o1[8];
        #pragma unroll
        for (int i = 0; i < 8; i++) {
            o0[i] = f2bf(silu_f(bf2f(t0u[i]) + bf2f(b0u[i])));
            o1[i] = f2bf(silu_f(bf2f(t1u[i]) + bf2f(b1u[i])));
        }
        af0 = *(const short8*)o0;
        af1 = *(const short8*)o1;
    } else if (quad == 0) {
        ridS[el] = -1;
    }

    // stage 2: m2 = A @ eW2 via MFMA (fragments already in registers)
    floatx4 acc[4];
    #pragma unroll
    for (int i = 0; i < 4; i++) acc[i] = (floatx4){0, 0, 0, 0};
    #pragma unroll
    for (int nt = 0; nt < 4; nt++) {
        short8 bf0 = *(const short8*)(Bp + (size_t)((0 * 4 + quad) * 64 + nt * 16 + lrow) * 8);
        acc[nt] = __builtin_amdgcn_mfma_f32_16x16x32_bf16(af0, bf0, acc[nt], 0, 0, 0);
        short8 bf1 = *(const short8*)(Bp + (size_t)((1 * 4 + quad) * 64 + nt * 16 + lrow) * 8);
        acc[nt] = __builtin_amdgcn_mfma_f32_16x16x32_bf16(af1, bf1, acc[nt], 0, 0, 0);
    }

    // stage 3: silu(m2 + b2) -> M2s (fp32)
    #pragma unroll
    for (int nt = 0; nt < 4; nt++) {
        int n = nt * 16 + lrow;
        float bv = b2[n];
        #pragma unroll
        for (int r = 0; r < 4; r++) {
            int el2 = wave * 16 + quad * 4 + r;
            M2s[el2 * 68 + n] = silu_f(acc[nt][r] + bv);
        }
    }
    __syncthreads();   // M2s + ridS complete block-wide

    // segment detection (wave 0)
    if (tid < 64) {
        bool st = (ridS[tid] >= 0) && (tid == 0 || ridS[tid] != ridS[tid - 1]);
        unsigned long long m = __ballot(st);
        if (st) {
            int pos = __popcll(m & ((1ull << tid) - 1));
            segStartS[pos] = (short)tid;
        }
        if (tid == 0) {
            int ns = __popcll(m);
            nsegS = ns;
            int nvalid = E - e0;
            if (nvalid > 64) nvalid = 64;
            segStartS[ns] = (short)nvalid;
        }
    }
    __syncthreads();

    // stage 4: segmented reduce; interior segments plain-store, edges atomic
    {
        int f = tid & 63;
        int g = tid >> 6;
        int ns = nsegS;
        for (int j = g; j < ns; j += 4) {
            int a = segStartS[j], b = segStartS[j + 1];
            float s = 0.0f;
            for (int el2 = a; el2 < b; el2++) s += M2s[el2 * 68 + f];
            int rv = ridS[a];
            if (j == 0 || j == ns - 1)
                atomicAdd(&agg[(size_t)rv * 64 + f], s);
            else
                agg[(size_t)rv * 64 + f] = s;
        }
    }
}

// ---------------------------------------------------------------------------
// Fused node-side chain (unchanged from R5). Residual in transposed fp32
// hFT[128][NR] (float4 I/O); epilogues round-trip LDS, stored as dwordx4.
// ---------------------------------------------------------------------------
#define SROW 264
template<int FINAL>
__global__ __launch_bounds__(256) void node_fused_k(
    const unsigned short* __restrict__ hbf, const float* __restrict__ agg,
    const unsigned short* __restrict__ W1, const float* __restrict__ b1,
    const unsigned short* __restrict__ W2, const float* __restrict__ b2,
    const unsigned short* __restrict__ B3, const float* __restrict__ bias3,
    float* __restrict__ hFT, unsigned short* __restrict__ hB,
    unsigned short* __restrict__ Pout, float* __restrict__ outF, int M)
{
    __shared__ unsigned short S[64 * SROW];
    const int tid = threadIdx.x;
    const int m0 = blockIdx.x * 64;
    const int wave = tid >> 6;
    const int lane = tid & 63;
    const int lrow = lane & 15;
    const int quad = lane >> 4;
    const int row0 = m0 + wave * 16 + quad * 4;

    floatx4 res4[8];
    #pragma unroll
    for (int nt = 0; nt < 8; nt++)
        res4[nt] = *(const floatx4*)(hFT + (size_t)(nt * 16 + lrow) * NR + row0);

    for (int t = tid; t < 64 * 24; t += 256) {
        int rr = t / 24, c = t % 24;
        int row = m0 + rr;
        uintx4 val = {0, 0, 0, 0};
        if (row < M) {
            if (c < 16) {
                val = *(const uintx4*)(hbf + (size_t)row * 128 + c * 8);
            } else {
                const floatx4* s4 = (const floatx4*)(agg + (size_t)row * 64 + (c - 16) * 8);
                floatx4 f0 = s4[0], f1 = s4[1];
                unsigned short tmp[8];
                #pragma unroll
                for (int i = 0; i < 4; i++) { tmp[i] = f2bf(f0[i]); tmp[4 + i] = f2bf(f1[i]); }
                val = *(const uintx4*)tmp;
            }
        }
        *(uintx4*)(&S[rr * SROW + c * 8]) = val;
    }
    __syncthreads();   // barrier 1

    floatx4 acc[8];
    #pragma unroll
    for (int i = 0; i < 8; i++) acc[i] = (floatx4){0, 0, 0, 0};
    {
        const unsigned short* arow = &S[(wave * 16 + lrow) * SROW];
        #pragma unroll
        for (int kt = 0; kt < 6; kt++) {
            short8 afrag = *(const short8*)(arow + kt * 32 + quad * 8);
            int kb = kt * 4 + quad;
            #pragma unroll
            for (int nt = 0; nt < 8; nt++) {
                short8 bfrag = *(const short8*)(W1 + (size_t)(kb * 128 + nt * 16 + lrow) * 8);
                acc[nt] = __builtin_amdgcn_mfma_f32_16x16x32_bf16(afrag, bfrag, acc[nt], 0, 0, 0);
            }
        }
    }

    #pragma unroll
    for (int nt = 0; nt < 8; nt++) {
        int n = nt * 16 + lrow;
        float bv = b1[n];
        #pragma unroll
        for (int r = 0; r < 4; r++) {
            int el = wave * 16 + quad * 4 + r;
            S[el * SROW + n] = f2bf(silu_f(acc[nt][r] + bv));
        }
    }

    floatx4 acc2[8];
    #pragma unroll
    for (int i = 0; i < 8; i++) acc2[i] = (floatx4){0, 0, 0, 0};
    {
        const unsigned short* arow = &S[(wave * 16 + lrow) * SROW];
        #pragma unroll
        for (int kt = 0; kt < 4; kt++) {
            short8 afrag = *(const short8*)(arow + kt * 32 + quad * 8);
            int kb = kt * 4 + quad;
            #pragma unroll
            for (int nt = 0; nt < 8; nt++) {
                short8 bfrag = *(const short8*)(W2 + (size_t)(kb * 128 + nt * 16 + lrow) * 8);
                acc2[nt] = __builtin_amdgcn_mfma_f32_16x16x32_bf16(afrag, bfrag, acc2[nt], 0, 0, 0);
            }
        }
    }

    #pragma unroll
    for (int nt = 0; nt < 8; nt++) {
        int n = nt * 16 + lrow;
        float bv = b2[n];
        floatx4 v4;
        #pragma unroll
        for (int r = 0; r < 4; r++) {
            int el = wave * 16 + quad * 4 + r;
            float v = acc2[nt][r] + bv + res4[nt][r];
            v4[r] = v;
            S[el * SROW + n] = f2bf(v);
        }
        if (!FINAL && row0 < M)
            *(floatx4*)(hFT + (size_t)n * NR + row0) = v4;
    }

    constexpr int NT3 = FINAL ? 4 : 8;
    constexpr int NO3 = FINAL ? 64 : 128;
    floatx4 acc3[NT3];
    #pragma unroll
    for (int i = 0; i < NT3; i++) acc3[i] = (floatx4){0, 0, 0, 0};
    {
        const unsigned short* arow = &S[(wave * 16 + lrow) * SROW];
        #pragma unroll
        for (int kt = 0; kt < 4; kt++) {
            short8 afrag = *(const short8*)(arow + kt * 32 + quad * 8);
            int kb = kt * 4 + quad;
            #pragma unroll
            for (int nt = 0; nt < NT3; nt++) {
                short8 bfrag = *(const short8*)(B3 + (size_t)(kb * NO3 + nt * 16 + lrow) * 8);
                acc3[nt] = __builtin_amdgcn_mfma_f32_16x16x32_bf16(afrag, bfrag, acc3[nt], 0, 0, 0);
            }
        }
    }
    #pragma unroll
    for (int nt = 0; nt < NT3; nt++) {
        int n = nt * 16 + lrow;
        float bv = bias3[n];
        #pragma unroll
        for (int r = 0; r < 4; r++) {
            int el = wave * 16 + quad * 4 + r;
            float v = acc3[nt][r] + bv;
            if (FINAL) ((float*)(&S[el * SROW + 128]))[n] = v;
            else       S[el * SROW + 128 + n] = f2bf(v);
        }
    }
    __syncthreads();   // barrier 2

    if (FINAL) {
        for (int t = tid; t < 64 * 16; t += 256) {
            int rr = t / 16, c = t % 16;
            int row = m0 + rr;
            if (row < M)
                *(floatx4*)(outF + (size_t)row * 64 + c * 4) =
                    *(const floatx4*)((const float*)(&S[rr * SROW + 128]) + c * 4);
        }
    } else {
        for (int t = tid; t < 64 * 32; t += 256) {
            int rr = t / 32, c = t % 32;
            int row = m0 + rr;
            if (row < M) {
                if (c < 16)
                    *(uintx4*)(hB + (size_t)row * 128 + c * 8) =
                        *(const uintx4*)(&S[rr * SROW + c * 8]);
                else
                    *(uintx4*)(Pout + (size_t)row * 128 + (c - 16) * 8) =
                        *(const uintx4*)(&S[rr * SROW + 128 + (c - 16) * 8]);
            }
        }
    }
}

// ---------------------------------------------------------------------------
// Fused embedding: h1 = h0 @ W_in + b_in -> hFT/hB, P0 = h1 @ W1'[0]
// ---------------------------------------------------------------------------
__global__ __launch_bounds__(256) void embed_fused_k(
    const unsigned short* __restrict__ h0bf, const unsigned short* __restrict__ Win,
    const float* __restrict__ b_in, const unsigned short* __restrict__ W1,
    const float* __restrict__ biasP, float* __restrict__ hFT,
    unsigned short* __restrict__ hB, unsigned short* __restrict__ Pout, int M)
{
    __shared__ unsigned short S[64 * SROW];
    const int tid = threadIdx.x;
    const int m0 = blockIdx.x * 64;
    const int wave = tid >> 6;
    const int lane = tid & 63;
    const int lrow = lane & 15;
    const int quad = lane >> 4;
    const int row0 = m0 + wave * 16 + quad * 4;

    for (int t = tid; t < 64 * 8; t += 256) {
        int rr = t >> 3, c = t & 7;
        int row = m0 + rr;
        uintx4 val = {0, 0, 0, 0};
        if (row < M) val = *(const uintx4*)(h0bf + (size_t)row * 64 + c * 8);
        *(uintx4*)(&S[rr * SROW + c * 8]) = val;
    }
    __syncthreads();   // barrier 1

    floatx4 acc[8];
    #pragma unroll
    for (int i = 0; i < 8; i++) acc[i] = (floatx4){0, 0, 0, 0};
    {
        const unsigned short* arow = &S[(wave * 16 + lrow) * SROW];
        #pragma unroll
        for (int kt = 0; kt < 2; kt++) {
            short8 afrag = *(const short8*)(arow + kt * 32 + quad * 8);
            int kb = kt * 4 + quad;
            #pragma unroll
            for (int nt = 0; nt < 8; nt++) {
                short8 bfrag = *(const short8*)(Win + (size_t)(kb * 128 + nt * 16 + lrow) * 8);
                acc[nt] = __builtin_amdgcn_mfma_f32_16x16x32_bf16(afrag, bfrag, acc[nt], 0, 0, 0);
            }
        }
    }

    #pragma unroll
    for (int nt = 0; nt < 8; nt++) {
        int n = nt * 16 + lrow;
        float bv = b_in[n];
        floatx4 v4;
        #pragma unroll
        for (int r = 0; r < 4; r++) {
            int el = wave * 16 + quad * 4 + r;
            float v = acc[nt][r] + bv;
            v4[r] = v;
            S[el * SROW + n] = f2bf(v);
        }
        if (row0 < M)
            *(floatx4*)(hFT + (size_t)n * NR + row0) = v4;
    }

    floatx4 acc3[8];
    #pragma unroll
    for (int i = 0; i < 8; i++) acc3[i] = (floatx4){0, 0, 0, 0};
    {
        const unsigned short* arow = &S[(wave * 16 + lrow) * SROW];
        #pragma unroll
        for (int kt = 0; kt < 4; kt++) {
            short8 afrag = *(const short8*)(arow + kt * 32 + quad * 8);
            int kb = kt * 4 + quad;
            #pragma unroll
            for (int nt = 0; nt < 8; nt++) {
                short8 bfrag = *(const short8*)(W1 + (size_t)(kb * 128 + nt * 16 + lrow) * 8);
                acc3[nt] = __builtin_amdgcn_mfma_f32_16x16x32_bf16(afrag, bfrag, acc3[nt], 0, 0, 0);
            }
        }
    }
    #pragma unroll
    for (int nt = 0; nt < 8; nt++) {
        int n = nt * 16 + lrow;
        float bv = biasP[n];
        #pragma unroll
        for (int r = 0; r < 4; r++) {
            int el = wave * 16 + quad * 4 + r;
            S[el * SROW + 128 + n] = f2bf(acc3[nt][r] + bv);
        }
    }
    __syncthreads();   // barrier 2

    for (int t = tid; t < 64 * 32; t += 256) {
        int rr = t / 32, c = t % 32;
        int row = m0 + rr;
        if (row < M) {
            if (c < 16)
                *(uintx4*)(hB + (size_t)row * 128 + c * 8) =
                    *(const uintx4*)(&S[rr * SROW + c * 8]);
            else
                *(uintx4*)(Pout + (size_t)row * 128 + (c - 16) * 8) =
                    *(const uintx4*)(&S[rr * SROW + 128 + (c - 16) * 8]);
        }
    }
}

// ---------------------------------------------------------------------------
extern "C" void kernel_launch(void* const* d_in, const int* in_sizes, int n_in,
                              void* d_out, int out_size, void* d_ws, size_t ws_size,
                              hipStream_t stream) {
    const float* h0   = (const float*)d_in[0];
    const int*   edges= (const int*)d_in[1];
    const float* W_in = (const float*)d_in[2];
    const float* b_in = (const float*)d_in[3];
    const float* eW1  = (const float*)d_in[4];
    const float* eb1  = (const float*)d_in[5];
    const float* eW2  = (const float*)d_in[6];
    const float* eb2  = (const float*)d_in[7];
    const float* nW1  = (const float*)d_in[8];
    const float* nb1  = (const float*)d_in[9];
    const float* nW2  = (const float*)d_in[10];
    const float* nb2  = (const float*)d_in[11];
    const float* W_out= (const float*)d_in[12];
    const float* b_out= (const float*)d_in[13];
    float* out = (float*)d_out;

    const int E = in_sizes[1] / 2;      // 800000
    const int* erow = edges;
    const int* ecol = edges + E;

    char* ws = (char*)d_ws;
    unsigned short* hbf  = (unsigned short*)(ws + 0);            // 12,800,000
    float*          hFT  = (float*)(ws + 12800000);              // 25,624,576 (128 x NR fp32)
    unsigned short* P    = (unsigned short*)(ws + 38424576);     // 12,800,000
    float*          agg  = (float*)(ws + 51224576);              // 12,800,000
    unsigned short* h0bf = (unsigned short*)(ws + 76824576);     //  6,400,000 (start only)
    int2*           eidx = (int2*)(ws + 76824576);               //  6,400,000 (aliases h0bf)
    float*          biasP= (float*)(ws + 83224576);              //  2,048
    unsigned short* Winp = (unsigned short*)(ws + 83226624);     // 16,384
    unsigned short* Woutp= (unsigned short*)(ws + 83243008);     // 16,384
    unsigned short* W1p  = (unsigned short*)(ws + 83259392);     // 131,072
    unsigned short* eW2p = (unsigned short*)(ws + 83390464);     // 32,768
    unsigned short* nW1p = (unsigned short*)(ws + 83423232);     // 196,608
    unsigned short* nW2p = (unsigned short*)(ws + 83619840);     // 131,072
    int*            counts=(int*)(ws + 83750912);                // 200,000
    int*            cursor=(int*)(ws + 83950912);                // 200,000
    int*            bsum = (int*)(ws + 84150912);                // 256

    const int gemm_grid = (N_NODES + 63) / 64;    // 782
    const int edge_grid = (E + 63) / 64;          // 12500
    const int pack_grid = (int)((PACK_TOTAL2 + 255) / 256);
    const int nb = (N_NODES + 1023) / 1024;       // 49

    hipMemsetAsync(counts, 0, (size_t)N_NODES * 4, stream);
    pack_kernel<<<pack_grid, 256, 0, stream>>>(h0, W_in, W_out, eW1, eb1, eW2,
                                               nW1, nW2, h0bf, Winp, Woutp, W1p,
                                               eW2p, nW1p, nW2p, biasP,
                                               erow, counts);

    // h1 = h0 @ W_in + b_in; P0 = h1 @ W1'[0]  (reads h0bf before eidx reuse)
    embed_fused_k<<<gemm_grid, 256, 0, stream>>>(
        h0bf, Winp, b_in, W1p, biasP, hFT, hbf, P, N_NODES);

    scan1_k<<<nb, 1024, 0, stream>>>(counts, cursor, bsum, N_NODES);
    scan2_k<<<1, 64, 0, stream>>>(bsum, nb);
    scan3_k<<<nb, 1024, 0, stream>>>(cursor, bsum, N_NODES);
    scatter_k<<<(E + 255) / 256, 256, 0, stream>>>(erow, ecol, cursor, eidx, E);

    for (int l = 0; l < 4; l++) {
        hipMemsetAsync(agg, 0, (size_t)N_NODES * 64 * 4, stream);
        edge_fused_k<<<edge_grid, 256, 0, stream>>>(
            eidx, P, eW2p + (size_t)l * SE2, eb2 + (size_t)l * 64, agg, E);
        if (l < 3) {
            node_fused_k<0><<<gemm_grid, 256, 0, stream>>>(
                hbf, agg, nW1p + (size_t)l * SN1, nb1 + (size_t)l * 128,
                nW2p + (size_t)l * SN2, nb2 + (size_t)l * 128,
                W1p + (size_t)(l + 1) * SW1, biasP + (size_t)(l + 1) * 128,
                hFT, hbf, P, nullptr, N_NODES);
        } else {
            node_fused_k<1><<<gemm_grid, 256, 0, stream>>>(
                hbf, agg, nW1p + (size_t)l * SN1, nb1 + (size_t)l * 128,
                nW2p + (size_t)l * SN2, nb2 + (size_t)l * 128,
                Woutp, b_out, hFT, hbf, nullptr, out, N_NODES);
        }
    }
}

// Round 7
// 471.310 us; speedup vs baseline: 1.4742x; 1.1220x over previous
//
#include <hip/hip_runtime.h>
#include <hip/hip_bf16.h>
#include <cstdint>
#include <cstddef>

#define N_NODES 50000
#define N_EDGES 800000
#define NR      50048    // N_NODES rounded up (hFT row stride, floats)
#define NBKT    196      // ceil(50000/256) buckets of 256 rows
#define BSH     8        // rows-per-bucket shift
#define BCHUNK  2048     // edges per bin_k block
#define CAP     6144     // max edges per bucket (mean 4082, sigma ~64)

typedef __attribute__((ext_vector_type(8))) short short8;
typedef __attribute__((ext_vector_type(4))) float floatx4;
typedef __attribute__((ext_vector_type(4))) unsigned int uintx4;

__device__ inline float bf2f(unsigned short u) {
    union { unsigned int i; float f; } v; v.i = ((unsigned int)u) << 16; return v.f;
}
__device__ inline unsigned short f2bf(float f) {
    union { float f; unsigned int i; } v; v.f = f;
    unsigned int u = v.i;
    return (unsigned short)((u + 0x7FFFu + ((u >> 16) & 1u)) >> 16);
}
// silu via v_rcp_f32 (1 ulp) instead of IEEE divide
__device__ inline float silu_f(float x) {
    float e = __expf(-x);
    return x * __builtin_amdgcn_rcpf(1.0f + e);
}

__device__ inline int block_excl_scan_256(int v, int* buf) {
    int tid = threadIdx.x;
    buf[tid] = v;
    __syncthreads();
    #pragma unroll
    for (int off = 1; off < 256; off <<= 1) {
        int t = (tid >= off) ? buf[tid - off] : 0;
        __syncthreads();
        buf[tid] += t;
        __syncthreads();
    }
    return buf[tid] - v;
}

// ---------------------------------------------------------------------------
// Pack kernel: fp32->bf16 conversions + weight rearrangement into MFMA
// B-fragment order: Bp[(kb*NOUT + n)*8 + i] = B[(kb*8+i)*NOUT + n]
// ---------------------------------------------------------------------------
__device__ inline void pack_std(const float* __restrict__ src,
                                unsigned short* __restrict__ dst,
                                int NOUT, long j) {
    int i = (int)(j & 7);
    long rest = j >> 3;
    int n = (int)(rest % NOUT);
    int kb = (int)(rest / NOUT);
    dst[j] = f2bf(src[(long)(kb * 8 + i) * NOUT + n]);
}

#define NH0   (N_NODES * 64L)
#define SW_IN 8192L
#define SW_OUT 8192L
#define SW1   16384L
#define SE2   4096L
#define SN1   24576L
#define SN2   16384L
#define SB    128L
#define PERL  (SW1 + SE2 + SN1 + SN2 + SB)
#define PACK_TOTAL (NH0 + SW_IN + SW_OUT + 4 * PERL)

__global__ __launch_bounds__(256) void pack_kernel(
    const float* __restrict__ h0, const float* __restrict__ W_in,
    const float* __restrict__ W_out, const float* __restrict__ eW1,
    const float* __restrict__ eb1, const float* __restrict__ eW2,
    const float* __restrict__ nW1, const float* __restrict__ nW2,
    unsigned short* __restrict__ h0bf, unsigned short* __restrict__ Winp,
    unsigned short* __restrict__ Woutp, unsigned short* __restrict__ W1p,
    unsigned short* __restrict__ eW2p, unsigned short* __restrict__ nW1p,
    unsigned short* __restrict__ nW2p, float* __restrict__ biasP)
{
    long idx = (long)blockIdx.x * 256 + threadIdx.x;
    if (idx >= PACK_TOTAL) return;
    long j = idx;
    if (j < NH0) { h0bf[j] = f2bf(h0[j]); return; }
    j -= NH0;
    if (j < SW_IN) { pack_std(W_in, Winp, 128, j); return; }
    j -= SW_IN;
    if (j < SW_OUT) { pack_std(W_out, Woutp, 64, j); return; }
    j -= SW_OUT;
    int l = (int)(j / PERL);
    long r = j % PERL;
    if (r < SW1) {
        int i = (int)(r & 7);
        int n = (int)((r >> 3) & 127);
        int kb = (int)(r >> 10);
        int k = kb * 8 + i;
        const float* w = eW1 + (long)l * 256 * 64;
        float v = (n < 64) ? w[(long)k * 64 + n] : w[(long)(128 + k) * 64 + (n - 64)];
        W1p[(long)l * SW1 + r] = f2bf(v);
        return;
    }
    r -= SW1;
    if (r < SE2) { pack_std(eW2 + (long)l * 4096, eW2p + (long)l * SE2, 64, r); return; }
    r -= SE2;
    if (r < SN1) { pack_std(nW1 + (long)l * 24576, nW1p + (long)l * SN1, 128, r); return; }
    r -= SN1;
    if (r < SN2) { pack_std(nW2 + (long)l * 16384, nW2p + (long)l * SN2, 128, r); return; }
    r -= SN2;
    biasP[(long)l * 128 + r] = (r < 64) ? eb1[(long)l * 64 + r] : 0.0f;
}

// ---------------------------------------------------------------------------
// Edge-sort pipeline: bucket histogram -> scan -> LDS-binned scatter ->
// per-bucket LDS counting sort with coalesced output. Avoids the random
// 64B-line write amplification of a direct scatter (52MB -> ~20MB).
// ---------------------------------------------------------------------------
__global__ __launch_bounds__(256) void hist_k(const int* __restrict__ erow,
                                              int* __restrict__ countB, int E) {
    __shared__ int c[NBKT];
    for (int i = threadIdx.x; i < NBKT; i += 256) c[i] = 0;
    __syncthreads();
    int j = blockIdx.x * BCHUNK + threadIdx.x;
    #pragma unroll
    for (int i = 0; i < BCHUNK / 256; i++, j += 256)
        if (j < E) atomicAdd(&c[erow[j] >> BSH], 1);
    __syncthreads();
    for (int i = threadIdx.x; i < NBKT; i += 256)
        if (c[i]) atomicAdd(&countB[i], c[i]);
}

__global__ __launch_bounds__(256) void bucket_scan_k(const int* __restrict__ countB,
                                                     int* __restrict__ bucketBase,
                                                     int* __restrict__ bucketCursor) {
    __shared__ int buf[256];
    int tid = threadIdx.x;
    int v = (tid < NBKT) ? countB[tid] : 0;
    int excl = block_excl_scan_256(v, buf);
    if (tid < NBKT) {
        bucketBase[tid] = excl;
        bucketCursor[tid] = excl;
    }
    if (tid == NBKT - 1) bucketBase[NBKT] = excl + v;   // = E
}

__global__ __launch_bounds__(256) void bin_k(
    const int* __restrict__ erow, const int* __restrict__ ecol,
    int* __restrict__ bucketCursor, int2* __restrict__ binned, int E)
{
    __shared__ int2 staged[BCHUNK];
    __shared__ int cnt[NBKT];
    __shared__ int binStart[NBKT];
    __shared__ int gbase[NBKT];
    __shared__ int scanbuf[256];
    const int tid = threadIdx.x;
    const int base = blockIdx.x * BCHUNK;
    const int nloc = min(BCHUNK, E - base);

    for (int i = tid; i < NBKT; i += 256) cnt[i] = 0;
    __syncthreads();

    int2 ed[BCHUNK / 256];
    int  bo[BCHUNK / 256];
    #pragma unroll
    for (int i = 0; i < BCHUNK / 256; i++) {
        int jl = i * 256 + tid;
        if (jl < nloc) {
            int j = base + jl;
            int r = erow[j], c = ecol[j];
            ed[i] = make_int2(r, c);
            int b = r >> BSH;
            int off = atomicAdd(&cnt[b], 1);
            bo[i] = (b << 12) | off;
        } else bo[i] = -1;
    }
    __syncthreads();

    int v = (tid < NBKT) ? cnt[tid] : 0;
    int excl = block_excl_scan_256(v, scanbuf);
    if (tid < NBKT) binStart[tid] = excl;
    if (tid < NBKT && v > 0) gbase[tid] = atomicAdd(&bucketCursor[tid], v);
    __syncthreads();

    #pragma unroll
    for (int i = 0; i < BCHUNK / 256; i++) {
        if (bo[i] >= 0)
            staged[binStart[bo[i] >> 12] + (bo[i] & 0xFFF)] = ed[i];
    }
    __syncthreads();

    for (int j = tid; j < nloc; j += 256) {
        int2 e = staged[j];
        int b = e.x >> BSH;
        binned[gbase[b] + (j - binStart[b])] = e;
    }
}

__global__ __launch_bounds__(256) void sort_k(
    const int2* __restrict__ binned, const int* __restrict__ bucketBase,
    int2* __restrict__ eidx)
{
    __shared__ int2 st[CAP];
    __shared__ int2 st2[CAP];
    __shared__ int cnt[256];
    __shared__ int cur[256];
    __shared__ int scanbuf[256];
    const int b = blockIdx.x;
    const int tid = threadIdx.x;
    const int s0 = bucketBase[b];
    int n = bucketBase[b + 1] - s0;
    if (n > CAP) n = CAP;    // memory-safety clamp (never hit for this graph)

    cnt[tid] = 0;
    __syncthreads();
    for (int j = tid; j < n; j += 256) {
        int2 e = binned[s0 + j];
        st[j] = e;
        atomicAdd(&cnt[e.x & 255], 1);
    }
    __syncthreads();
    int excl = block_excl_scan_256(cnt[tid], scanbuf);
    cur[tid] = excl;
    __syncthreads();
    for (int j = tid; j < n; j += 256) {
        int2 e = st[j];
        int pos = atomicAdd(&cur[e.x & 255], 1);
        st2[pos] = e;
    }
    __syncthreads();
    for (int j = tid; j < n; j += 256)
        eidx[s0 + j] = st2[j];
}

// ---------------------------------------------------------------------------
// Fused edge + block-segmented aggregate over sorted edges (unchanged R6).
// A-fragments gathered straight into registers.
// ---------------------------------------------------------------------------
__global__ __launch_bounds__(256) void edge_fused_k(
    const int2* __restrict__ eidx,
    const unsigned short* __restrict__ P,    // [N,128]: 0..63 top(+b1), 64..127 bot
    const unsigned short* __restrict__ Bp,   // eW2 frag order
    const float* __restrict__ b2, float* __restrict__ agg, int E)
{
    __shared__ float M2s[64 * 68];
    __shared__ int ridS[64];
    __shared__ short segStartS[66];
    __shared__ int nsegS;
    const int tid = threadIdx.x;
    const int wave = tid >> 6;
    const int lane = tid & 63;
    const int lrow = lane & 15;
    const int quad = lane >> 4;
    const int e0 = blockIdx.x * 64;
    const int el = wave * 16 + lrow;
    const int e = e0 + el;

    short8 af0 = {0, 0, 0, 0, 0, 0, 0, 0};
    short8 af1 = af0;
    if (e < E) {
        int2 rc = eidx[e];
        int rr = rc.x, cc = rc.y;
        if (quad == 0) ridS[el] = rr;
        const uintx4* pt = (const uintx4*)(P + (size_t)rr * 128 + quad * 8);
        const uintx4* pb = (const uintx4*)(P + (size_t)cc * 128 + 64 + quad * 8);
        uintx4 t0 = pt[0], t1 = pt[4];
        uintx4 b0 = pb[0], b1 = pb[4];
        const unsigned short* t0u = (const unsigned short*)&t0;
        const unsigned short* t1u = (const unsigned short*)&t1;
        const unsigned short* b0u = (const unsigned short*)&b0;
        const unsigned short* b1u = (const unsigned short*)&b1;
        unsigned short o0[8], o1[8];
        #pragma unroll
        for (int i = 0; i < 8; i++) {
            o0[i] = f2bf(silu_f(bf2f(t0u[i]) + bf2f(b0u[i])));
            o1[i] = f2bf(silu_f(bf2f(t1u[i]) + bf2f(b1u[i])));
        }
        af0 = *(const short8*)o0;
        af1 = *(const short8*)o1;
    } else if (quad == 0) {
        ridS[el] = -1;
    }

    floatx4 acc[4];
    #pragma unroll
    for (int i = 0; i < 4; i++) acc[i] = (floatx4){0, 0, 0, 0};
    #pragma unroll
    for (int nt = 0; nt < 4; nt++) {
        short8 bf0 = *(const short8*)(Bp + (size_t)((0 * 4 + quad) * 64 + nt * 16 + lrow) * 8);
        acc[nt] = __builtin_amdgcn_mfma_f32_16x16x32_bf16(af0, bf0, acc[nt], 0, 0, 0);
        short8 bf1 = *(const short8*)(Bp + (size_t)((1 * 4 + quad) * 64 + nt * 16 + lrow) * 8);
        acc[nt] = __builtin_amdgcn_mfma_f32_16x16x32_bf16(af1, bf1, acc[nt], 0, 0, 0);
    }

    #pragma unroll
    for (int nt = 0; nt < 4; nt++) {
        int n = nt * 16 + lrow;
        float bv = b2[n];
        #pragma unroll
        for (int r = 0; r < 4; r++) {
            int el2 = wave * 16 + quad * 4 + r;
            M2s[el2 * 68 + n] = silu_f(acc[nt][r] + bv);
        }
    }
    __syncthreads();

    if (tid < 64) {
        bool st = (ridS[tid] >= 0) && (tid == 0 || ridS[tid] != ridS[tid - 1]);
        unsigned long long m = __ballot(st);
        if (st) {
            int pos = __popcll(m & ((1ull << tid) - 1));
            segStartS[pos] = (short)tid;
        }
        if (tid == 0) {
            int ns = __popcll(m);
            nsegS = ns;
            int nvalid = E - e0;
            if (nvalid > 64) nvalid = 64;
            segStartS[ns] = (short)nvalid;
        }
    }
    __syncthreads();

    {
        int f = tid & 63;
        int g = tid >> 6;
        int ns = nsegS;
        for (int j = g; j < ns; j += 4) {
            int a = segStartS[j], b = segStartS[j + 1];
            float s = 0.0f;
            for (int el2 = a; el2 < b; el2++) s += M2s[el2 * 68 + f];
            int rv = ridS[a];
            if (j == 0 || j == ns - 1)
                atomicAdd(&agg[(size_t)rv * 64 + f], s);
            else
                agg[(size_t)rv * 64 + f] = s;
        }
    }
}

// ---------------------------------------------------------------------------
// Fused node-side chain (unchanged from R5/R6).
// ---------------------------------------------------------------------------
#define SROW 264
template<int FINAL>
__global__ __launch_bounds__(256) void node_fused_k(
    const unsigned short* __restrict__ hbf, const float* __restrict__ agg,
    const unsigned short* __restrict__ W1, const float* __restrict__ b1,
    const unsigned short* __restrict__ W2, const float* __restrict__ b2,
    const unsigned short* __restrict__ B3, const float* __restrict__ bias3,
    float* __restrict__ hFT, unsigned short* __restrict__ hB,
    unsigned short* __restrict__ Pout, float* __restrict__ outF, int M)
{
    __shared__ unsigned short S[64 * SROW];
    const int tid = threadIdx.x;
    const int m0 = blockIdx.x * 64;
    const int wave = tid >> 6;
    const int lane = tid & 63;
    const int lrow = lane & 15;
    const int quad = lane >> 4;
    const int row0 = m0 + wave * 16 + quad * 4;

    floatx4 res4[8];
    #pragma unroll
    for (int nt = 0; nt < 8; nt++)
        res4[nt] = *(const floatx4*)(hFT + (size_t)(nt * 16 + lrow) * NR + row0);

    for (int t = tid; t < 64 * 24; t += 256) {
        int rr = t / 24, c = t % 24;
        int row = m0 + rr;
        uintx4 val = {0, 0, 0, 0};
        if (row < M) {
            if (c < 16) {
                val = *(const uintx4*)(hbf + (size_t)row * 128 + c * 8);
            } else {
                const floatx4* s4 = (const floatx4*)(agg + (size_t)row * 64 + (c - 16) * 8);
                floatx4 f0 = s4[0], f1 = s4[1];
                unsigned short tmp[8];
                #pragma unroll
                for (int i = 0; i < 4; i++) { tmp[i] = f2bf(f0[i]); tmp[4 + i] = f2bf(f1[i]); }
                val = *(const uintx4*)tmp;
            }
        }
        *(uintx4*)(&S[rr * SROW + c * 8]) = val;
    }
    __syncthreads();   // barrier 1

    floatx4 acc[8];
    #pragma unroll
    for (int i = 0; i < 8; i++) acc[i] = (floatx4){0, 0, 0, 0};
    {
        const unsigned short* arow = &S[(wave * 16 + lrow) * SROW];
        #pragma unroll
        for (int kt = 0; kt < 6; kt++) {
            short8 afrag = *(const short8*)(arow + kt * 32 + quad * 8);
            int kb = kt * 4 + quad;
            #pragma unroll
            for (int nt = 0; nt < 8; nt++) {
                short8 bfrag = *(const short8*)(W1 + (size_t)(kb * 128 + nt * 16 + lrow) * 8);
                acc[nt] = __builtin_amdgcn_mfma_f32_16x16x32_bf16(afrag, bfrag, acc[nt], 0, 0, 0);
            }
        }
    }

    #pragma unroll
    for (int nt = 0; nt < 8; nt++) {
        int n = nt * 16 + lrow;
        float bv = b1[n];
        #pragma unroll
        for (int r = 0; r < 4; r++) {
            int el = wave * 16 + quad * 4 + r;
            S[el * SROW + n] = f2bf(silu_f(acc[nt][r] + bv));
        }
    }

    floatx4 acc2[8];
    #pragma unroll
    for (int i = 0; i < 8; i++) acc2[i] = (floatx4){0, 0, 0, 0};
    {
        const unsigned short* arow = &S[(wave * 16 + lrow) * SROW];
        #pragma unroll
        for (int kt = 0; kt < 4; kt++) {
            short8 afrag = *(const short8*)(arow + kt * 32 + quad * 8);
            int kb = kt * 4 + quad;
            #pragma unroll
            for (int nt = 0; nt < 8; nt++) {
                short8 bfrag = *(const short8*)(W2 + (size_t)(kb * 128 + nt * 16 + lrow) * 8);
                acc2[nt] = __builtin_amdgcn_mfma_f32_16x16x32_bf16(afrag, bfrag, acc2[nt], 0, 0, 0);
            }
        }
    }

    #pragma unroll
    for (int nt = 0; nt < 8; nt++) {
        int n = nt * 16 + lrow;
        float bv = b2[n];
        floatx4 v4;
        #pragma unroll
        for (int r = 0; r < 4; r++) {
            int el = wave * 16 + quad * 4 + r;
            float v = acc2[nt][r] + bv + res4[nt][r];
            v4[r] = v;
            S[el * SROW + n] = f2bf(v);
        }
        if (!FINAL && row0 < M)
            *(floatx4*)(hFT + (size_t)n * NR + row0) = v4;
    }

    constexpr int NT3 = FINAL ? 4 : 8;
    constexpr int NO3 = FINAL ? 64 : 128;
    floatx4 acc3[NT3];
    #pragma unroll
    for (int i = 0; i < NT3; i++) acc3[i] = (floatx4){0, 0, 0, 0};
    {
        const unsigned short* arow = &S[(wave * 16 + lrow) * SROW];
        #pragma unroll
        for (int kt = 0; kt < 4; kt++) {
            short8 afrag = *(const short8*)(arow + kt * 32 + quad * 8);
            int kb = kt * 4 + quad;
            #pragma unroll
            for (int nt = 0; nt < NT3; nt++) {
                short8 bfrag = *(const short8*)(B3 + (size_t)(kb * NO3 + nt * 16 + lrow) * 8);
                acc3[nt] = __builtin_amdgcn_mfma_f32_16x16x32_bf16(afrag, bfrag, acc3[nt], 0, 0, 0);
            }
        }
    }
    #pragma unroll
    for (int nt = 0; nt < NT3; nt++) {
        int n = nt * 16 + lrow;
        float bv = bias3[n];
        #pragma unroll
        for (int r = 0; r < 4; r++) {
            int el = wave * 16 + quad * 4 + r;
            float v = acc3[nt][r] + bv;
            if (FINAL) ((float*)(&S[el * SROW + 128]))[n] = v;
            else       S[el * SROW + 128 + n] = f2bf(v);
        }
    }
    __syncthreads();   // barrier 2

    if (FINAL) {
        for (int t = tid; t < 64 * 16; t += 256) {
            int rr = t / 16, c = t % 16;
            int row = m0 + rr;
            if (row < M)
                *(floatx4*)(outF + (size_t)row * 64 + c * 4) =
                    *(const floatx4*)((const float*)(&S[rr * SROW + 128]) + c * 4);
        }
    } else {
        for (int t = tid; t < 64 * 32; t += 256) {
            int rr = t / 32, c = t % 32;
            int row = m0 + rr;
            if (row < M) {
                if (c < 16)
                    *(uintx4*)(hB + (size_t)row * 128 + c * 8) =
                        *(const uintx4*)(&S[rr * SROW + c * 8]);
                else
                    *(uintx4*)(Pout + (size_t)row * 128 + (c - 16) * 8) =
                        *(const uintx4*)(&S[rr * SROW + 128 + (c - 16) * 8]);
            }
        }
    }
}

// ---------------------------------------------------------------------------
// Fused embedding: h1 = h0 @ W_in + b_in -> hFT/hB, P0 = h1 @ W1'[0]
// ---------------------------------------------------------------------------
__global__ __launch_bounds__(256) void embed_fused_k(
    const unsigned short* __restrict__ h0bf, const unsigned short* __restrict__ Win,
    const float* __restrict__ b_in, const unsigned short* __restrict__ W1,
    const float* __restrict__ biasP, float* __restrict__ hFT,
    unsigned short* __restrict__ hB, unsigned short* __restrict__ Pout, int M)
{
    __shared__ unsigned short S[64 * SROW];
    const int tid = threadIdx.x;
    const int m0 = blockIdx.x * 64;
    const int wave = tid >> 6;
    const int lane = tid & 63;
    const int lrow = lane & 15;
    const int quad = lane >> 4;
    const int row0 = m0 + wave * 16 + quad * 4;

    for (int t = tid; t < 64 * 8; t += 256) {
        int rr = t >> 3, c = t & 7;
        int row = m0 + rr;
        uintx4 val = {0, 0, 0, 0};
        if (row < M) val = *(const uintx4*)(h0bf + (size_t)row * 64 + c * 8);
        *(uintx4*)(&S[rr * SROW + c * 8]) = val;
    }
    __syncthreads();   // barrier 1

    floatx4 acc[8];
    #pragma unroll
    for (int i = 0; i < 8; i++) acc[i] = (floatx4){0, 0, 0, 0};
    {
        const unsigned short* arow = &S[(wave * 16 + lrow) * SROW];
        #pragma unroll
        for (int kt = 0; kt < 2; kt++) {
            short8 afrag = *(const short8*)(arow + kt * 32 + quad * 8);
            int kb = kt * 4 + quad;
            #pragma unroll
            for (int nt = 0; nt < 8; nt++) {
                short8 bfrag = *(const short8*)(Win + (size_t)(kb * 128 + nt * 16 + lrow) * 8);
                acc[nt] = __builtin_amdgcn_mfma_f32_16x16x32_bf16(afrag, bfrag, acc[nt], 0, 0, 0);
            }
        }
    }

    #pragma unroll
    for (int nt = 0; nt < 8; nt++) {
        int n = nt * 16 + lrow;
        float bv = b_in[n];
        floatx4 v4;
        #pragma unroll
        for (int r = 0; r < 4; r++) {
            int el = wave * 16 + quad * 4 + r;
            float v = acc[nt][r] + bv;
            v4[r] = v;
            S[el * SROW + n] = f2bf(v);
        }
        if (row0 < M)
            *(floatx4*)(hFT + (size_t)n * NR + row0) = v4;
    }

    floatx4 acc3[8];
    #pragma unroll
    for (int i = 0; i < 8; i++) acc3[i] = (floatx4){0, 0, 0, 0};
    {
        const unsigned short* arow = &S[(wave * 16 + lrow) * SROW];
        #pragma unroll
        for (int kt = 0; kt < 4; kt++) {
            short8 afrag = *(const short8*)(arow + kt * 32 + quad * 8);
            int kb = kt * 4 + quad;
            #pragma unroll
            for (int nt = 0; nt < 8; nt++) {
                short8 bfrag = *(const short8*)(W1 + (size_t)(kb * 128 + nt * 16 + lrow) * 8);
                acc3[nt] = __builtin_amdgcn_mfma_f32_16x16x32_bf16(afrag, bfrag, acc3[nt], 0, 0, 0);
            }
        }
    }
    #pragma unroll
    for (int nt = 0; nt < 8; nt++) {
        int n = nt * 16 + lrow;
        float bv = biasP[n];
        #pragma unroll
        for (int r = 0; r < 4; r++) {
            int el = wave * 16 + quad * 4 + r;
            S[el * SROW + 128 + n] = f2bf(acc3[nt][r] + bv);
        }
    }
    __syncthreads();   // barrier 2

    for (int t = tid; t < 64 * 32; t += 256) {
        int rr = t / 32, c = t % 32;
        int row = m0 + rr;
        if (row < M) {
            if (c < 16)
                *(uintx4*)(hB + (size_t)row * 128 + c * 8) =
                    *(const uintx4*)(&S[rr * SROW + c * 8]);
            else
                *(uintx4*)(Pout + (size_t)row * 128 + (c - 16) * 8) =
                    *(const uintx4*)(&S[rr * SROW + 128 + (c - 16) * 8]);
        }
    }
}

// ---------------------------------------------------------------------------
extern "C" void kernel_launch(void* const* d_in, const int* in_sizes, int n_in,
                              void* d_out, int out_size, void* d_ws, size_t ws_size,
                              hipStream_t stream) {
    const float* h0   = (const float*)d_in[0];
    const int*   edges= (const int*)d_in[1];
    const float* W_in = (const float*)d_in[2];
    const float* b_in = (const float*)d_in[3];
    const float* eW1  = (const float*)d_in[4];
    const float* eb1  = (const float*)d_in[5];
    const float* eW2  = (const float*)d_in[6];
    const float* eb2  = (const float*)d_in[7];
    const float* nW1  = (const float*)d_in[8];
    const float* nb1  = (const float*)d_in[9];
    const float* nW2  = (const float*)d_in[10];
    const float* nb2  = (const float*)d_in[11];
    const float* W_out= (const float*)d_in[12];
    const float* b_out= (const float*)d_in[13];
    float* out = (float*)d_out;

    const int E = in_sizes[1] / 2;      // 800000
    const int* erow = edges;
    const int* ecol = edges + E;

    char* ws = (char*)d_ws;
    unsigned short* hbf  = (unsigned short*)(ws + 0);            // 12,800,000
    float*          hFT  = (float*)(ws + 12800000);              // 25,624,576 (128 x NR fp32)
    unsigned short* P    = (unsigned short*)(ws + 38424576);     // 12,800,000
    float*          agg  = (float*)(ws + 51224576);              // 12,800,000
    int2*           binned=(int2*)(ws + 51224576);               //  6,400,000 (aliases agg; consumed pre-memset)
    unsigned short* h0bf = (unsigned short*)(ws + 76824576);     //  6,400,000 (start only)
    int2*           eidx = (int2*)(ws + 76824576);               //  6,400,000 (aliases h0bf; written after embed)
    float*          biasP= (float*)(ws + 83224576);              //  2,048
    unsigned short* Winp = (unsigned short*)(ws + 83226624);     // 16,384
    unsigned short* Woutp= (unsigned short*)(ws + 83243008);     // 16,384
    unsigned short* W1p  = (unsigned short*)(ws + 83259392);     // 131,072
    unsigned short* eW2p = (unsigned short*)(ws + 83390464);     // 32,768
    unsigned short* nW1p = (unsigned short*)(ws + 83423232);     // 196,608
    unsigned short* nW2p = (unsigned short*)(ws + 83619840);     // 131,072
    int*            countB=(int*)(ws + 83750912);                // 784
    int*            bucketBase=(int*)(ws + 83751936);            // 788
    int*            bucketCursor=(int*)(ws + 83752960);          // 784

    const int gemm_grid = (N_NODES + 63) / 64;    // 782
    const int edge_grid = (E + 63) / 64;          // 12500
    const int pack_grid = (int)((PACK_TOTAL + 255) / 256);
    const int bin_grid  = (E + BCHUNK - 1) / BCHUNK;   // 391

    hipMemsetAsync(countB, 0, NBKT * 4, stream);
    pack_kernel<<<pack_grid, 256, 0, stream>>>(h0, W_in, W_out, eW1, eb1, eW2,
                                               nW1, nW2, h0bf, Winp, Woutp, W1p,
                                               eW2p, nW1p, nW2p, biasP);

    // h1 = h0 @ W_in + b_in; P0 = h1 @ W1'[0]  (reads h0bf before eidx reuse)
    embed_fused_k<<<gemm_grid, 256, 0, stream>>>(
        h0bf, Winp, b_in, W1p, biasP, hFT, hbf, P, N_NODES);

    // edge sort pipeline (runs after embed: eidx aliases h0bf)
    hist_k<<<bin_grid, 256, 0, stream>>>(erow, countB, E);
    bucket_scan_k<<<1, 256, 0, stream>>>(countB, bucketBase, bucketCursor);
    bin_k<<<bin_grid, 256, 0, stream>>>(erow, ecol, bucketCursor, binned, E);
    sort_k<<<NBKT, 256, 0, stream>>>(binned, bucketBase, eidx);

    for (int l = 0; l < 4; l++) {
        hipMemsetAsync(agg, 0, (size_t)N_NODES * 64 * 4, stream);
        edge_fused_k<<<edge_grid, 256, 0, stream>>>(
            eidx, P, eW2p + (size_t)l * SE2, eb2 + (size_t)l * 64, agg, E);
        if (l < 3) {
            node_fused_k<0><<<gemm_grid, 256, 0, stream>>>(
                hbf, agg, nW1p + (size_t)l * SN1, nb1 + (size_t)l * 128,
                nW2p + (size_t)l * SN2, nb2 + (size_t)l * 128,
                W1p + (size_t)(l + 1) * SW1, biasP + (size_t)(l + 1) * 128,
                hFT, hbf, P, nullptr, N_NODES);
        } else {
            node_fused_k<1><<<gemm_grid, 256, 0, stream>>>(
                hbf, agg, nW1p + (size_t)l * SN1, nb1 + (size_t)l * 128,
                nW2p + (size_t)l * SN2, nb2 + (size_t)l * 128,
                Woutp, b_out, hFT, hbf, nullptr, out, N_NODES);
        }
    }
}

// Round 8
// 436.926 us; speedup vs baseline: 1.5902x; 1.0787x over previous
//
#include <hip/hip_runtime.h>
#include <hip/hip_bf16.h>
#include <cstdint>
#include <cstddef>

#define N_NODES 50000
#define N_EDGES 800000
#define NR      50048    // N_NODES rounded up (hFT row stride, floats)
#define NBKT    196      // ceil(50000/256) buckets of 256 rows
#define BSH     8        // rows-per-bucket shift
#define BCHUNK  2048     // edges per bin_k block
#define CAP     6144     // max edges per bucket (mean 4082)

typedef __attribute__((ext_vector_type(8))) short short8;
typedef __attribute__((ext_vector_type(4))) float floatx4;
typedef __attribute__((ext_vector_type(4))) unsigned int uintx4;

__device__ inline float bf2f(unsigned short u) {
    union { unsigned int i; float f; } v; v.i = ((unsigned int)u) << 16; return v.f;
}
__device__ inline unsigned short f2bf(float f) {
    union { float f; unsigned int i; } v; v.f = f;
    unsigned int u = v.i;
    return (unsigned short)((u + 0x7FFFu + ((u >> 16) & 1u)) >> 16);
}
// packed RNE f32x2 -> bf16x2 (v_cvt_pk_bf16_f32 on gfx950)
__device__ inline unsigned int f2bf_pk(float a, float b) {
    __hip_bfloat162 h2 = __float22bfloat162_rn(make_float2(a, b));
    return *reinterpret_cast<unsigned int*>(&h2);
}
// unpack 2 bf16 (packed in a uint) to 2 floats
__device__ inline float2 bf2f2(unsigned int u) {
    union { unsigned int i; float f; } lo, hi;
    lo.i = u << 16;
    hi.i = u & 0xFFFF0000u;
    return make_float2(lo.f, hi.f);
}
// silu via v_rcp_f32 (1 ulp) instead of IEEE divide
__device__ inline float silu_f(float x) {
    float e = __expf(-x);
    return x * __builtin_amdgcn_rcpf(1.0f + e);
}

__device__ inline int block_excl_scan_256(int v, int* buf) {
    int tid = threadIdx.x;
    buf[tid] = v;
    __syncthreads();
    #pragma unroll
    for (int off = 1; off < 256; off <<= 1) {
        int t = (tid >= off) ? buf[tid - off] : 0;
        __syncthreads();
        buf[tid] += t;
        __syncthreads();
    }
    return buf[tid] - v;
}

// ---------------------------------------------------------------------------
// Pack kernel: fp32->bf16 conversions + weight rearrangement into MFMA
// B-fragment order: Bp[(kb*NOUT + n)*8 + i] = B[(kb*8+i)*NOUT + n]
// ---------------------------------------------------------------------------
__device__ inline void pack_std(const float* __restrict__ src,
                                unsigned short* __restrict__ dst,
                                int NOUT, long j) {
    int i = (int)(j & 7);
    long rest = j >> 3;
    int n = (int)(rest % NOUT);
    int kb = (int)(rest / NOUT);
    dst[j] = f2bf(src[(long)(kb * 8 + i) * NOUT + n]);
}

#define NH0   (N_NODES * 64L)
#define SW_IN 8192L
#define SW_OUT 8192L
#define SW1   16384L
#define SE2   4096L
#define SN1   24576L
#define SN2   16384L
#define SB    128L
#define PERL  (SW1 + SE2 + SN1 + SN2 + SB)
#define PACK_TOTAL (NH0 + SW_IN + SW_OUT + 4 * PERL)

__global__ __launch_bounds__(256) void pack_kernel(
    const float* __restrict__ h0, const float* __restrict__ W_in,
    const float* __restrict__ W_out, const float* __restrict__ eW1,
    const float* __restrict__ eb1, const float* __restrict__ eW2,
    const float* __restrict__ nW1, const float* __restrict__ nW2,
    unsigned short* __restrict__ h0bf, unsigned short* __restrict__ Winp,
    unsigned short* __restrict__ Woutp, unsigned short* __restrict__ W1p,
    unsigned short* __restrict__ eW2p, unsigned short* __restrict__ nW1p,
    unsigned short* __restrict__ nW2p, float* __restrict__ biasP)
{
    long idx = (long)blockIdx.x * 256 + threadIdx.x;
    if (idx >= PACK_TOTAL) return;
    long j = idx;
    if (j < NH0) { h0bf[j] = f2bf(h0[j]); return; }
    j -= NH0;
    if (j < SW_IN) { pack_std(W_in, Winp, 128, j); return; }
    j -= SW_IN;
    if (j < SW_OUT) { pack_std(W_out, Woutp, 64, j); return; }
    j -= SW_OUT;
    int l = (int)(j / PERL);
    long r = j % PERL;
    if (r < SW1) {
        int i = (int)(r & 7);
        int n = (int)((r >> 3) & 127);
        int kb = (int)(r >> 10);
        int k = kb * 8 + i;
        const float* w = eW1 + (long)l * 256 * 64;
        float v = (n < 64) ? w[(long)k * 64 + n] : w[(long)(128 + k) * 64 + (n - 64)];
        W1p[(long)l * SW1 + r] = f2bf(v);
        return;
    }
    r -= SW1;
    if (r < SE2) { pack_std(eW2 + (long)l * 4096, eW2p + (long)l * SE2, 64, r); return; }
    r -= SE2;
    if (r < SN1) { pack_std(nW1 + (long)l * 24576, nW1p + (long)l * SN1, 128, r); return; }
    r -= SN1;
    if (r < SN2) { pack_std(nW2 + (long)l * 16384, nW2p + (long)l * SN2, 128, r); return; }
    r -= SN2;
    biasP[(long)l * 128 + r] = (r < 64) ? eb1[(long)l * 64 + r] : 0.0f;
}

// ---------------------------------------------------------------------------
// Edge-sort pipeline (unchanged from R7)
// ---------------------------------------------------------------------------
__global__ __launch_bounds__(256) void hist_k(const int* __restrict__ erow,
                                              int* __restrict__ countB, int E) {
    __shared__ int c[NBKT];
    for (int i = threadIdx.x; i < NBKT; i += 256) c[i] = 0;
    __syncthreads();
    int j = blockIdx.x * BCHUNK + threadIdx.x;
    #pragma unroll
    for (int i = 0; i < BCHUNK / 256; i++, j += 256)
        if (j < E) atomicAdd(&c[erow[j] >> BSH], 1);
    __syncthreads();
    for (int i = threadIdx.x; i < NBKT; i += 256)
        if (c[i]) atomicAdd(&countB[i], c[i]);
}

__global__ __launch_bounds__(256) void bucket_scan_k(const int* __restrict__ countB,
                                                     int* __restrict__ bucketBase,
                                                     int* __restrict__ bucketCursor) {
    __shared__ int buf[256];
    int tid = threadIdx.x;
    int v = (tid < NBKT) ? countB[tid] : 0;
    int excl = block_excl_scan_256(v, buf);
    if (tid < NBKT) {
        bucketBase[tid] = excl;
        bucketCursor[tid] = excl;
    }
    if (tid == NBKT - 1) bucketBase[NBKT] = excl + v;   // = E
}

__global__ __launch_bounds__(256) void bin_k(
    const int* __restrict__ erow, const int* __restrict__ ecol,
    int* __restrict__ bucketCursor, int2* __restrict__ binned, int E)
{
    __shared__ int2 staged[BCHUNK];
    __shared__ int cnt[NBKT];
    __shared__ int binStart[NBKT];
    __shared__ int gbase[NBKT];
    __shared__ int scanbuf[256];
    const int tid = threadIdx.x;
    const int base = blockIdx.x * BCHUNK;
    const int nloc = min(BCHUNK, E - base);

    for (int i = tid; i < NBKT; i += 256) cnt[i] = 0;
    __syncthreads();

    int2 ed[BCHUNK / 256];
    int  bo[BCHUNK / 256];
    #pragma unroll
    for (int i = 0; i < BCHUNK / 256; i++) {
        int jl = i * 256 + tid;
        if (jl < nloc) {
            int j = base + jl;
            int r = erow[j], c = ecol[j];
            ed[i] = make_int2(r, c);
            int b = r >> BSH;
            int off = atomicAdd(&cnt[b], 1);
            bo[i] = (b << 12) | off;
        } else bo[i] = -1;
    }
    __syncthreads();

    int v = (tid < NBKT) ? cnt[tid] : 0;
    int excl = block_excl_scan_256(v, scanbuf);
    if (tid < NBKT) binStart[tid] = excl;
    if (tid < NBKT && v > 0) gbase[tid] = atomicAdd(&bucketCursor[tid], v);
    __syncthreads();

    #pragma unroll
    for (int i = 0; i < BCHUNK / 256; i++) {
        if (bo[i] >= 0)
            staged[binStart[bo[i] >> 12] + (bo[i] & 0xFFF)] = ed[i];
    }
    __syncthreads();

    for (int j = tid; j < nloc; j += 256) {
        int2 e = staged[j];
        int b = e.x >> BSH;
        binned[gbase[b] + (j - binStart[b])] = e;
    }
}

__global__ __launch_bounds__(256) void sort_k(
    const int2* __restrict__ binned, const int* __restrict__ bucketBase,
    int2* __restrict__ eidx)
{
    __shared__ int2 st[CAP];
    __shared__ int2 st2[CAP];
    __shared__ int cnt[256];
    __shared__ int cur[256];
    __shared__ int scanbuf[256];
    const int b = blockIdx.x;
    const int tid = threadIdx.x;
    const int s0 = bucketBase[b];
    int n = bucketBase[b + 1] - s0;
    if (n > CAP) n = CAP;

    cnt[tid] = 0;
    __syncthreads();
    for (int j = tid; j < n; j += 256) {
        int2 e = binned[s0 + j];
        st[j] = e;
        atomicAdd(&cnt[e.x & 255], 1);
    }
    __syncthreads();
    int excl = block_excl_scan_256(cnt[tid], scanbuf);
    cur[tid] = excl;
    __syncthreads();
    for (int j = tid; j < n; j += 256) {
        int2 e = st[j];
        int pos = atomicAdd(&cur[e.x & 255], 1);
        st2[pos] = e;
    }
    __syncthreads();
    for (int j = tid; j < n; j += 256)
        eidx[s0 + j] = st2[j];
}

// ---------------------------------------------------------------------------
// Fused edge + block-segmented aggregate over sorted edges.
// R8: packed bf16 conversions in the gather/silu stage.
// ---------------------------------------------------------------------------
__global__ __launch_bounds__(256) void edge_fused_k(
    const int2* __restrict__ eidx,
    const unsigned short* __restrict__ P,    // [N,128]: 0..63 top(+b1), 64..127 bot
    const unsigned short* __restrict__ Bp,   // eW2 frag order
    const float* __restrict__ b2, float* __restrict__ agg, int E)
{
    __shared__ float M2s[64 * 68];
    __shared__ int ridS[64];
    __shared__ short segStartS[66];
    __shared__ int nsegS;
    const int tid = threadIdx.x;
    const int wave = tid >> 6;
    const int lane = tid & 63;
    const int lrow = lane & 15;
    const int quad = lane >> 4;
    const int e0 = blockIdx.x * 64;
    const int el = wave * 16 + lrow;
    const int e = e0 + el;

    short8 af0 = {0, 0, 0, 0, 0, 0, 0, 0};
    short8 af1 = af0;
    if (e < E) {
        int2 rc = eidx[e];
        int rr = rc.x, cc = rc.y;
        if (quad == 0) ridS[el] = rr;
        const uintx4* pt = (const uintx4*)(P + (size_t)rr * 128 + quad * 8);
        const uintx4* pb = (const uintx4*)(P + (size_t)cc * 128 + 64 + quad * 8);
        uintx4 t0 = pt[0], t1 = pt[4];
        uintx4 b0 = pb[0], b1 = pb[4];
        const unsigned int* t0u = (const unsigned int*)&t0;
        const unsigned int* t1u = (const unsigned int*)&t1;
        const unsigned int* b0u = (const unsigned int*)&b0;
        const unsigned int* b1u = (const unsigned int*)&b1;
        unsigned int o0[4], o1[4];
        #pragma unroll
        for (int i = 0; i < 4; i++) {
            float2 a0 = bf2f2(t0u[i]), c0 = bf2f2(b0u[i]);
            o0[i] = f2bf_pk(silu_f(a0.x + c0.x), silu_f(a0.y + c0.y));
            float2 a1 = bf2f2(t1u[i]), c1 = bf2f2(b1u[i]);
            o1[i] = f2bf_pk(silu_f(a1.x + c1.x), silu_f(a1.y + c1.y));
        }
        af0 = *(const short8*)o0;
        af1 = *(const short8*)o1;
    } else if (quad == 0) {
        ridS[el] = -1;
    }

    floatx4 acc[4];
    #pragma unroll
    for (int i = 0; i < 4; i++) acc[i] = (floatx4){0, 0, 0, 0};
    #pragma unroll
    for (int nt = 0; nt < 4; nt++) {
        short8 bf0 = *(const short8*)(Bp + (size_t)((0 * 4 + quad) * 64 + nt * 16 + lrow) * 8);
        acc[nt] = __builtin_amdgcn_mfma_f32_16x16x32_bf16(af0, bf0, acc[nt], 0, 0, 0);
        short8 bf1 = *(const short8*)(Bp + (size_t)((1 * 4 + quad) * 64 + nt * 16 + lrow) * 8);
        acc[nt] = __builtin_amdgcn_mfma_f32_16x16x32_bf16(af1, bf1, acc[nt], 0, 0, 0);
    }

    #pragma unroll
    for (int nt = 0; nt < 4; nt++) {
        int n = nt * 16 + lrow;
        float bv = b2[n];
        #pragma unroll
        for (int r = 0; r < 4; r++) {
            int el2 = wave * 16 + quad * 4 + r;
            M2s[el2 * 68 + n] = silu_f(acc[nt][r] + bv);
        }
    }
    __syncthreads();

    if (tid < 64) {
        bool st = (ridS[tid] >= 0) && (tid == 0 || ridS[tid] != ridS[tid - 1]);
        unsigned long long m = __ballot(st);
        if (st) {
            int pos = __popcll(m & ((1ull << tid) - 1));
            segStartS[pos] = (short)tid;
        }
        if (tid == 0) {
            int ns = __popcll(m);
            nsegS = ns;
            int nvalid = E - e0;
            if (nvalid > 64) nvalid = 64;
            segStartS[ns] = (short)nvalid;
        }
    }
    __syncthreads();

    {
        int f = tid & 63;
        int g = tid >> 6;
        int ns = nsegS;
        for (int j = g; j < ns; j += 4) {
            int a = segStartS[j], b = segStartS[j + 1];
            float s = 0.0f;
            for (int el2 = a; el2 < b; el2++) s += M2s[el2 * 68 + f];
            int rv = ridS[a];
            if (j == 0 || j == ns - 1)
                atomicAdd(&agg[(size_t)rv * 64 + f], s);
            else
                agg[(size_t)rv * 64 + f] = s;
        }
    }
}

// ---------------------------------------------------------------------------
// Fused node-side chain, R8: 512 threads / 8 waves. Wave (g,h) owns row
// group g (16 rows) x N-half h (64 cols). LDS col partitions per row
// (stride SROW=336 shorts): staged [0,192) -> t [192,320) -> h_new [0,128)
// -> P [128,256). No wave-pair write/read overlap; 4 barriers.
// Also zeroes its own agg rows for the next layer (replaces memset).
// ---------------------------------------------------------------------------
#define SROW 336
template<int FINAL>
__global__ __launch_bounds__(512) void node_fused_k(
    const unsigned short* __restrict__ hbf, const float* __restrict__ agg,
    const unsigned short* __restrict__ W1, const float* __restrict__ b1,
    const unsigned short* __restrict__ W2, const float* __restrict__ b2,
    const unsigned short* __restrict__ B3, const float* __restrict__ bias3,
    float* __restrict__ hFT, unsigned short* __restrict__ hB,
    unsigned short* __restrict__ Pout, float* __restrict__ outF,
    float* __restrict__ aggZ, int M)
{
    __shared__ unsigned short S[64 * SROW];
    const int tid = threadIdx.x;
    const int m0 = blockIdx.x * 64;
    const int wave = tid >> 6;
    const int lane = tid & 63;
    const int lrow = lane & 15;
    const int quad = lane >> 4;
    const int g = wave >> 1;          // row group 0..3
    const int h = wave & 1;           // N half
    const int row0 = m0 + g * 16 + quad * 4;
    const int elb = g * 16 + quad * 4;

    // residual prefetch: this wave's 4 feature-frags (transposed hFT, float4)
    floatx4 res4[4];
    #pragma unroll
    for (int j = 0; j < 4; j++) {
        int n = (4 * h + j) * 16 + lrow;
        res4[j] = *(const floatx4*)(hFT + (size_t)n * NR + row0);
    }

    // staging: [h(128 bf16) | agg(64 fp32->bf16)] -> S cols 0..191
    for (int t = tid; t < 64 * 24; t += 512) {
        int rr = t / 24, c = t % 24;
        int row = m0 + rr;
        uintx4 val = {0, 0, 0, 0};
        if (row < M) {
            if (c < 16) {
                val = *(const uintx4*)(hbf + (size_t)row * 128 + c * 8);
            } else {
                const floatx4* s4 = (const floatx4*)(agg + (size_t)row * 64 + (c - 16) * 8);
                floatx4 f0 = s4[0], f1 = s4[1];
                unsigned int tmp[4];
                tmp[0] = f2bf_pk(f0[0], f0[1]);
                tmp[1] = f2bf_pk(f0[2], f0[3]);
                tmp[2] = f2bf_pk(f1[0], f1[1]);
                tmp[3] = f2bf_pk(f1[2], f1[3]);
                val = *(const uintx4*)tmp;
            }
        }
        *(uintx4*)(&S[rr * SROW + c * 8]) = val;
    }
    __syncthreads();   // B1: staging complete (all agg reads done)

    // zero this block's agg rows for the next layer (replaces hipMemsetAsync)
    if (!FINAL) {
        floatx4 z = {0, 0, 0, 0};
        for (int t = tid; t < 64 * 16; t += 512) {
            int rr = t >> 4, c = t & 15;
            int row = m0 + rr;
            if (row < M) *(floatx4*)(aggZ + (size_t)row * 64 + c * 4) = z;
        }
    }

    const unsigned short* arow = &S[(g * 16 + lrow) * SROW];

    // ---- phase A MFMA: K=192, this wave's 4 n-frags ----
    floatx4 acc[4];
    #pragma unroll
    for (int i = 0; i < 4; i++) acc[i] = (floatx4){0, 0, 0, 0};
    #pragma unroll
    for (int kt = 0; kt < 6; kt++) {
        short8 afrag = *(const short8*)(arow + kt * 32 + quad * 8);
        int kb = kt * 4 + quad;
        #pragma unroll
        for (int j = 0; j < 4; j++) {
            int n = (4 * h + j) * 16 + lrow;
            short8 bfrag = *(const short8*)(W1 + (size_t)(kb * 128 + n) * 8);
            acc[j] = __builtin_amdgcn_mfma_f32_16x16x32_bf16(afrag, bfrag, acc[j], 0, 0, 0);
        }
    }

    // epilogue A: t -> S cols 192..319 (disjoint from staged region)
    #pragma unroll
    for (int j = 0; j < 4; j++) {
        int n = (4 * h + j) * 16 + lrow;
        float bv = b1[n];
        unsigned int p01 = f2bf_pk(silu_f(acc[j][0] + bv), silu_f(acc[j][1] + bv));
        unsigned int p23 = f2bf_pk(silu_f(acc[j][2] + bv), silu_f(acc[j][3] + bv));
        S[(elb + 0) * SROW + 192 + n] = (unsigned short)(p01 & 0xFFFF);
        S[(elb + 1) * SROW + 192 + n] = (unsigned short)(p01 >> 16);
        S[(elb + 2) * SROW + 192 + n] = (unsigned short)(p23 & 0xFFFF);
        S[(elb + 3) * SROW + 192 + n] = (unsigned short)(p23 >> 16);
    }
    __syncthreads();   // B2: t complete

    // ---- phase B MFMA: K=128 over t ----
    floatx4 acc2[4];
    #pragma unroll
    for (int i = 0; i < 4; i++) acc2[i] = (floatx4){0, 0, 0, 0};
    #pragma unroll
    for (int kt = 0; kt < 4; kt++) {
        short8 afrag = *(const short8*)(arow + 192 + kt * 32 + quad * 8);
        int kb = kt * 4 + quad;
        #pragma unroll
        for (int j = 0; j < 4; j++) {
            int n = (4 * h + j) * 16 + lrow;
            short8 bfrag = *(const short8*)(W2 + (size_t)(kb * 128 + n) * 8);
            acc2[j] = __builtin_amdgcn_mfma_f32_16x16x32_bf16(afrag, bfrag, acc2[j], 0, 0, 0);
        }
    }

    // epilogue B: h_new = acc2 + b2 + res -> S cols 0..127 + hFT (float4)
    #pragma unroll
    for (int j = 0; j < 4; j++) {
        int n = (4 * h + j) * 16 + lrow;
        float bv = b2[n];
        floatx4 v4;
        #pragma unroll
        for (int r = 0; r < 4; r++) v4[r] = acc2[j][r] + bv + res4[j][r];
        unsigned int p01 = f2bf_pk(v4[0], v4[1]);
        unsigned int p23 = f2bf_pk(v4[2], v4[3]);
        S[(elb + 0) * SROW + n] = (unsigned short)(p01 & 0xFFFF);
        S[(elb + 1) * SROW + n] = (unsigned short)(p01 >> 16);
        S[(elb + 2) * SROW + n] = (unsigned short)(p23 & 0xFFFF);
        S[(elb + 3) * SROW + n] = (unsigned short)(p23 >> 16);
        if (!FINAL && row0 < M)
            *(floatx4*)(hFT + (size_t)n * NR + row0) = v4;
    }
    __syncthreads();   // B3: h_new complete

    // ---- phase C MFMA: K=128 -> P (128) or out (64) ----
    constexpr int NT3 = FINAL ? 2 : 4;
    constexpr int NO3 = FINAL ? 64 : 128;
    floatx4 acc3[NT3];
    #pragma unroll
    for (int i = 0; i < NT3; i++) acc3[i] = (floatx4){0, 0, 0, 0};
    #pragma unroll
    for (int kt = 0; kt < 4; kt++) {
        short8 afrag = *(const short8*)(arow + kt * 32 + quad * 8);
        int kb = kt * 4 + quad;
        #pragma unroll
        for (int j = 0; j < NT3; j++) {
            int n = (NT3 * h + j) * 16 + lrow;
            short8 bfrag = *(const short8*)(B3 + (size_t)(kb * NO3 + n) * 8);
            acc3[j] = __builtin_amdgcn_mfma_f32_16x16x32_bf16(afrag, bfrag, acc3[j], 0, 0, 0);
        }
    }
    // epilogue C -> S cols 128..255 (bf16 P) or fp32 out region (same cols)
    #pragma unroll
    for (int j = 0; j < NT3; j++) {
        int n = (NT3 * h + j) * 16 + lrow;
        float bv = bias3[n];
        if (FINAL) {
            #pragma unroll
            for (int r = 0; r < 4; r++)
                ((float*)(&S[(elb + r) * SROW + 128]))[n] = acc3[j][r] + bv;
        } else {
            unsigned int p01 = f2bf_pk(acc3[j][0] + bv, acc3[j][1] + bv);
            unsigned int p23 = f2bf_pk(acc3[j][2] + bv, acc3[j][3] + bv);
            S[(elb + 0) * SROW + 128 + n] = (unsigned short)(p01 & 0xFFFF);
            S[(elb + 1) * SROW + 128 + n] = (unsigned short)(p01 >> 16);
            S[(elb + 2) * SROW + 128 + n] = (unsigned short)(p23 & 0xFFFF);
            S[(elb + 3) * SROW + 128 + n] = (unsigned short)(p23 >> 16);
        }
    }
    __syncthreads();   // B4

    // cooperative wide stores
    if (FINAL) {
        for (int t = tid; t < 64 * 16; t += 512) {
            int rr = t >> 4, c = t & 15;
            int row = m0 + rr;
            if (row < M)
                *(floatx4*)(outF + (size_t)row * 64 + c * 4) =
                    *(const floatx4*)((const float*)(&S[rr * SROW + 128]) + c * 4);
        }
    } else {
        for (int t = tid; t < 64 * 32; t += 512) {
            int rr = t >> 5, c = t & 31;
            int row = m0 + rr;
            if (row < M) {
                if (c < 16)
                    *(uintx4*)(hB + (size_t)row * 128 + c * 8) =
                        *(const uintx4*)(&S[rr * SROW + c * 8]);
                else
                    *(uintx4*)(Pout + (size_t)row * 128 + (c - 16) * 8) =
                        *(const uintx4*)(&S[rr * SROW + 128 + (c - 16) * 8]);
            }
        }
    }
}

// ---------------------------------------------------------------------------
// Fused embedding (256 thr, wave-private rows as before, packed cvts)
// ---------------------------------------------------------------------------
#define SROWE 264
__global__ __launch_bounds__(256) void embed_fused_k(
    const unsigned short* __restrict__ h0bf, const unsigned short* __restrict__ Win,
    const float* __restrict__ b_in, const unsigned short* __restrict__ W1,
    const float* __restrict__ biasP, float* __restrict__ hFT,
    unsigned short* __restrict__ hB, unsigned short* __restrict__ Pout, int M)
{
    __shared__ unsigned short S[64 * SROWE];
    const int tid = threadIdx.x;
    const int m0 = blockIdx.x * 64;
    const int wave = tid >> 6;
    const int lane = tid & 63;
    const int lrow = lane & 15;
    const int quad = lane >> 4;
    const int row0 = m0 + wave * 16 + quad * 4;
    const int elb = wave * 16 + quad * 4;

    for (int t = tid; t < 64 * 8; t += 256) {
        int rr = t >> 3, c = t & 7;
        int row = m0 + rr;
        uintx4 val = {0, 0, 0, 0};
        if (row < M) val = *(const uintx4*)(h0bf + (size_t)row * 64 + c * 8);
        *(uintx4*)(&S[rr * SROWE + c * 8]) = val;
    }
    __syncthreads();   // barrier 1

    const unsigned short* arow = &S[(wave * 16 + lrow) * SROWE];

    floatx4 acc[8];
    #pragma unroll
    for (int i = 0; i < 8; i++) acc[i] = (floatx4){0, 0, 0, 0};
    #pragma unroll
    for (int kt = 0; kt < 2; kt++) {
        short8 afrag = *(const short8*)(arow + kt * 32 + quad * 8);
        int kb = kt * 4 + quad;
        #pragma unroll
        for (int nt = 0; nt < 8; nt++) {
            short8 bfrag = *(const short8*)(Win + (size_t)(kb * 128 + nt * 16 + lrow) * 8);
            acc[nt] = __builtin_amdgcn_mfma_f32_16x16x32_bf16(afrag, bfrag, acc[nt], 0, 0, 0);
        }
    }

    // epilogue: h1 -> S cols 0..127 (bf16) + hFT float4 (wave-private rows)
    #pragma unroll
    for (int nt = 0; nt < 8; nt++) {
        int n = nt * 16 + lrow;
        float bv = b_in[n];
        floatx4 v4;
        #pragma unroll
        for (int r = 0; r < 4; r++) v4[r] = acc[nt][r] + bv;
        unsigned int p01 = f2bf_pk(v4[0], v4[1]);
        unsigned int p23 = f2bf_pk(v4[2], v4[3]);
        S[(elb + 0) * SROWE + n] = (unsigned short)(p01 & 0xFFFF);
        S[(elb + 1) * SROWE + n] = (unsigned short)(p01 >> 16);
        S[(elb + 2) * SROWE + n] = (unsigned short)(p23 & 0xFFFF);
        S[(elb + 3) * SROWE + n] = (unsigned short)(p23 >> 16);
        if (row0 < M)
            *(floatx4*)(hFT + (size_t)n * NR + row0) = v4;
    }

    floatx4 acc3[8];
    #pragma unroll
    for (int i = 0; i < 8; i++) acc3[i] = (floatx4){0, 0, 0, 0};
    #pragma unroll
    for (int kt = 0; kt < 4; kt++) {
        short8 afrag = *(const short8*)(arow + kt * 32 + quad * 8);
        int kb = kt * 4 + quad;
        #pragma unroll
        for (int nt = 0; nt < 8; nt++) {
            short8 bfrag = *(const short8*)(W1 + (size_t)(kb * 128 + nt * 16 + lrow) * 8);
            acc3[nt] = __builtin_amdgcn_mfma_f32_16x16x32_bf16(afrag, bfrag, acc3[nt], 0, 0, 0);
        }
    }
    #pragma unroll
    for (int nt = 0; nt < 8; nt++) {
        int n = nt * 16 + lrow;
        float bv = biasP[n];
        unsigned int p01 = f2bf_pk(acc3[nt][0] + bv, acc3[nt][1] + bv);
        unsigned int p23 = f2bf_pk(acc3[nt][2] + bv, acc3[nt][3] + bv);
        S[(elb + 0) * SROWE + 128 + n] = (unsigned short)(p01 & 0xFFFF);
        S[(elb + 1) * SROWE + 128 + n] = (unsigned short)(p01 >> 16);
        S[(elb + 2) * SROWE + 128 + n] = (unsigned short)(p23 & 0xFFFF);
        S[(elb + 3) * SROWE + 128 + n] = (unsigned short)(p23 >> 16);
    }
    __syncthreads();   // barrier 2

    for (int t = tid; t < 64 * 32; t += 256) {
        int rr = t / 32, c = t % 32;
        int row = m0 + rr;
        if (row < M) {
            if (c < 16)
                *(uintx4*)(hB + (size_t)row * 128 + c * 8) =
                    *(const uintx4*)(&S[rr * SROWE + c * 8]);
            else
                *(uintx4*)(Pout + (size_t)row * 128 + (c - 16) * 8) =
                    *(const uintx4*)(&S[rr * SROWE + 128 + (c - 16) * 8]);
        }
    }
}

// ---------------------------------------------------------------------------
extern "C" void kernel_launch(void* const* d_in, const int* in_sizes, int n_in,
                              void* d_out, int out_size, void* d_ws, size_t ws_size,
                              hipStream_t stream) {
    const float* h0   = (const float*)d_in[0];
    const int*   edges= (const int*)d_in[1];
    const float* W_in = (const float*)d_in[2];
    const float* b_in = (const float*)d_in[3];
    const float* eW1  = (const float*)d_in[4];
    const float* eb1  = (const float*)d_in[5];
    const float* eW2  = (const float*)d_in[6];
    const float* eb2  = (const float*)d_in[7];
    const float* nW1  = (const float*)d_in[8];
    const float* nb1  = (const float*)d_in[9];
    const float* nW2  = (const float*)d_in[10];
    const float* nb2  = (const float*)d_in[11];
    const float* W_out= (const float*)d_in[12];
    const float* b_out= (const float*)d_in[13];
    float* out = (float*)d_out;

    const int E = in_sizes[1] / 2;      // 800000
    const int* erow = edges;
    const int* ecol = edges + E;

    char* ws = (char*)d_ws;
    unsigned short* hbf  = (unsigned short*)(ws + 0);            // 12,800,000
    float*          hFT  = (float*)(ws + 12800000);              // 25,624,576 (128 x NR fp32)
    unsigned short* P    = (unsigned short*)(ws + 38424576);     // 12,800,000
    float*          agg  = (float*)(ws + 51224576);              // 12,800,000
    int2*           binned=(int2*)(ws + 51224576);               //  6,400,000 (aliases agg; consumed pre-memset)
    unsigned short* h0bf = (unsigned short*)(ws + 76824576);     //  6,400,000 (start only)
    int2*           eidx = (int2*)(ws + 76824576);               //  6,400,000 (aliases h0bf; written after embed)
    float*          biasP= (float*)(ws + 83224576);              //  2,048
    unsigned short* Winp = (unsigned short*)(ws + 83226624);     // 16,384
    unsigned short* Woutp= (unsigned short*)(ws + 83243008);     // 16,384
    unsigned short* W1p  = (unsigned short*)(ws + 83259392);     // 131,072
    unsigned short* eW2p = (unsigned short*)(ws + 83390464);     // 32,768
    unsigned short* nW1p = (unsigned short*)(ws + 83423232);     // 196,608
    unsigned short* nW2p = (unsigned short*)(ws + 83619840);     // 131,072
    int*            countB=(int*)(ws + 83750912);                // 784
    int*            bucketBase=(int*)(ws + 83751936);            // 788
    int*            bucketCursor=(int*)(ws + 83752960);          // 784

    const int gemm_grid = (N_NODES + 63) / 64;    // 782
    const int edge_grid = (E + 63) / 64;          // 12500
    const int pack_grid = (int)((PACK_TOTAL + 255) / 256);
    const int bin_grid  = (E + BCHUNK - 1) / BCHUNK;   // 391

    hipMemsetAsync(countB, 0, NBKT * 4, stream);
    pack_kernel<<<pack_grid, 256, 0, stream>>>(h0, W_in, W_out, eW1, eb1, eW2,
                                               nW1, nW2, h0bf, Winp, Woutp, W1p,
                                               eW2p, nW1p, nW2p, biasP);

    // binning can run before embed (binned aliases agg, unused until layers)
    hist_k<<<bin_grid, 256, 0, stream>>>(erow, countB, E);
    bucket_scan_k<<<1, 256, 0, stream>>>(countB, bucketBase, bucketCursor);
    bin_k<<<bin_grid, 256, 0, stream>>>(erow, ecol, bucketCursor, binned, E);

    // h1 = h0 @ W_in + b_in; P0 = h1 @ W1'[0]  (reads h0bf before eidx reuse)
    embed_fused_k<<<gemm_grid, 256, 0, stream>>>(
        h0bf, Winp, b_in, W1p, biasP, hFT, hbf, P, N_NODES);

    // sort after embed (eidx aliases h0bf); consumes binned (agg region)
    sort_k<<<NBKT, 256, 0, stream>>>(binned, bucketBase, eidx);

    // single agg zero for layer 0 (subsequent layers zeroed by node_fused)
    hipMemsetAsync(agg, 0, (size_t)N_NODES * 64 * 4, stream);

    for (int l = 0; l < 4; l++) {
        edge_fused_k<<<edge_grid, 256, 0, stream>>>(
            eidx, P, eW2p + (size_t)l * SE2, eb2 + (size_t)l * 64, agg, E);
        if (l < 3) {
            node_fused_k<0><<<gemm_grid, 512, 0, stream>>>(
                hbf, agg, nW1p + (size_t)l * SN1, nb1 + (size_t)l * 128,
                nW2p + (size_t)l * SN2, nb2 + (size_t)l * 128,
                W1p + (size_t)(l + 1) * SW1, biasP + (size_t)(l + 1) * 128,
                hFT, hbf, P, nullptr, agg, N_NODES);
        } else {
            node_fused_k<1><<<gemm_grid, 512, 0, stream>>>(
                hbf, agg, nW1p + (size_t)l * SN1, nb1 + (size_t)l * 128,
                nW2p + (size_t)l * SN2, nb2 + (size_t)l * 128,
                Woutp, b_out, hFT, hbf, nullptr, out, nullptr, N_NODES);
        }
    }
}